// Round 11
// baseline (1167.414 us; speedup 1.0000x reference)
//
#include <hip/hip_runtime.h>
#include <math.h>

// ---------------------------------------------------------------------------
// MACE layer, round 17: fused scatter, take 2 — ZERO buffering of TP results.
//  - Empirical rule from r11..r16 (6 experiments): any variant that buffers
//    TP message components across the store point (LDS or registers)
//    corrupts v-components; immediate stores always pass. So: r15-exact
//    L1..L4 pipeline, and each (row, channel) message is atomicAdd'ed into
//    acc IMMEDIATELY after computation (no pms staging at all).
//  - k_gather and wm deleted; single k_mlp launch over all EE edges;
//    messages f32 end-to-end.
//  - Everything else byte-identical to round 15.
//
// Workspace (floats, ~52 MB used):
//   s_up   [N*64  f16]  @ 0
//   v_up   [N*192 f16]  @ 1048576
//   acc    [N*256 f32]  @ 4194304   (zeroed per call; atomic target)
//   fragw  [268 frags]  @ 12582912  (68608-f slot)
//   row_st [32832 int]  @ 12651520
//   cursor [32768 int]  @ 12684352
//   elist  [262144 int] @ 12717120
//   nperm  [33280 int]  @ 12979264  (memset -1)
//   tspec  [2304 int]   @ 13012544
//   sbins  [64 int]     @ 13014848
//   bcnt   [1280 int]   @ 13014912
//   bbase  [1280 int]   @ 13016192
// ---------------------------------------------------------------------------

#define NN 32768
#define EE 262144
#define ZZ 10
#define NB 128                           // NN/256 blocks for binning
#define NT_MAX 2064                      // >= ceil((NN + ZZ*15)/16), even
#define INV8 0.125f                      // 1/sqrt(64)
#define INV_SQRT8 0.35355339059327373f   // 1/sqrt(8)
#define INVZ 0.039528470752104741f       // 1/sqrt(64*10)
#define EPS_C 0.25f
#define RS2 0.70710678118654752f         // 1/sqrt(2)

typedef _Float16 f16;
typedef f16 f16x8 __attribute__((ext_vector_type(8)));
typedef f16 f16x4 __attribute__((ext_vector_type(4)));
typedef f16 f16x2 __attribute__((ext_vector_type(2)));
typedef float f32x4 __attribute__((ext_vector_type(4)));

#define LDFRAG(fid) (*(const f16x8*)(fragw + ((size_t)(fid) << 9) + (lane << 3)))

__device__ __forceinline__ unsigned short f2h(float x) {
  union { f16 h; unsigned short u; } cv;
  cv.h = (f16)x;
  return cv.u;
}

__device__ __forceinline__ f16x8 pack8(float4 a, float4 b) {
  f16x8 r;
  r[0] = (f16)a.x; r[1] = (f16)a.y; r[2] = (f16)a.z; r[3] = (f16)a.w;
  r[4] = (f16)b.x; r[5] = (f16)b.y; r[6] = (f16)b.z; r[7] = (f16)b.w;
  return r;
}

__device__ __forceinline__ float silu_f(float x) {
  return x / (1.0f + __expf(-x));
}

// ---------------------------------------------------------------------------
// Weight fragment packing (unchanged from round 15).
// ---------------------------------------------------------------------------
__global__ __launch_bounds__(256) void k_frag(
    const float* __restrict__ W1, const float* __restrict__ W2,
    const float* __restrict__ W3, const float* __restrict__ W4,
    const float* __restrict__ Wdns, const float* __restrict__ Wdnv,
    const float* __restrict__ Wpss, const float* __restrict__ Wpsv,
    const float* __restrict__ Wsks, const float* __restrict__ Wskv,
    const float* __restrict__ Wups, const float* __restrict__ Wupv,
    unsigned short* __restrict__ fragw) {
  int id = blockIdx.x * 256 + threadIdx.x;
  if (id >= 268 * 64) return;
  int fid = id >> 6, lane = id & 63;
  int q = lane >> 4, c = lane & 15;
  const float* W; int K = 64, N = 64, t, ks; float sc; int w4 = 0;
  if (fid < 4)       { W = W1; K = 8; N = 64; t = fid; ks = 0; sc = INV_SQRT8; }
  else if (fid < 12) { W = W2; t = (fid - 4) >> 1;  ks = (fid - 4) & 1;  sc = INV8; }
  else if (fid < 20) { W = W3; t = (fid - 12) >> 1; ks = (fid - 12) & 1; sc = INV8; }
  else if (fid < 60) { W = W4; N = 320; t = (fid - 20) >> 1; ks = (fid - 20) & 1; sc = INV8; w4 = 1; }
  else {
    int f2 = fid - 60; sc = INV8;
    if (f2 < 8)        { W = Wdns; }
    else if (f2 < 16)  { W = Wdnv; f2 -= 8; }
    else if (f2 < 24)  { W = Wpss; f2 -= 16; }
    else if (f2 < 32)  { W = Wpsv; f2 -= 24; }
    else if (f2 < 112) { f2 -= 32; W = Wsks + (f2 >> 3) * 4096; f2 &= 7; sc = INVZ; }
    else if (f2 < 192) { f2 -= 112; W = Wskv + (f2 >> 3) * 4096; f2 &= 7; sc = INVZ; }
    else if (f2 < 200) { W = Wups; f2 -= 192; }
    else               { W = Wupv; f2 -= 200; }
    t = f2 >> 1; ks = f2 & 1;
  }
  int col = w4 ? ((t % 5) * 64 + 4 * c + (t / 5)) : (t * 16 + c);
  unsigned short o[8];
#pragma unroll
  for (int i = 0; i < 8; ++i) {
    int k = ks * 32 + 8 * q + i;
    float v = (k < K) ? W[k * N + col] * sc : 0.0f;
    o[i] = f2h(v);
  }
  *(uint4*)(fragw + (size_t)id * 8) = *(const uint4*)o;
}

__global__ __launch_bounds__(256) void k_hist(const int* __restrict__ rcv,
                                              int* __restrict__ cnt) {
  int e = blockIdx.x * 256 + threadIdx.x;
  atomicAdd(&cnt[rcv[e]], 1);
}

__global__ __launch_bounds__(1024) void k_scan(const int* __restrict__ cnt,
                                               int* __restrict__ row_start,
                                               int* __restrict__ cursor) {
  __shared__ int tot[1024];
  int t = threadIdx.x;
  int base = t * 32;
  int local[32];
  int s = 0;
#pragma unroll
  for (int i = 0; i < 32; ++i) { local[i] = s; s += cnt[base + i]; }
  tot[t] = s;
  __syncthreads();
  for (int off = 1; off < 1024; off <<= 1) {
    int v = (t >= off) ? tot[t - off] : 0;
    __syncthreads();
    tot[t] += v;
    __syncthreads();
  }
  int prefix = (t == 0) ? 0 : tot[t - 1];
#pragma unroll
  for (int i = 0; i < 32; ++i) {
    int v = prefix + local[i];
    row_start[base + i] = v;
    cursor[base + i] = v;
  }
  if (t == 1023) row_start[NN] = prefix + s;
}

__global__ __launch_bounds__(256) void k_fill(const int* __restrict__ rcv,
                                              int* __restrict__ cursor,
                                              int* __restrict__ elist) {
  int e = blockIdx.x * 256 + threadIdx.x;
  int pos = atomicAdd(&cursor[rcv[e]], 1);
  elist[pos] = e;
}

// ---- node species binning, hierarchical (unchanged) ----
__global__ __launch_bounds__(256) void k_nhist(const int* __restrict__ species,
                                               int* __restrict__ sbins,
                                               int* __restrict__ bcnt) {
  __shared__ int h[ZZ];
  int t = threadIdx.x;
  if (t < ZZ) h[t] = 0;
  __syncthreads();
  int n = blockIdx.x * 256 + t;
  atomicAdd(&h[species[n]], 1);
  __syncthreads();
  if (t < ZZ) {
    bcnt[blockIdx.x * ZZ + t] = h[t];
    atomicAdd(&sbins[32 + t], h[t]);
  }
}

__global__ __launch_bounds__(256) void k_nscan(int* __restrict__ sbins,
                                               const int* __restrict__ bcnt,
                                               int* __restrict__ bbase,
                                               int* __restrict__ tspec) {
  __shared__ int sb[12];
  int t = threadIdx.x;
  if (t == 0) {
    int off = 0;
    for (int z = 0; z < ZZ; ++z) {
      sb[z] = off;
      off += ((sbins[32 + z] + 15) >> 4) << 4;
    }
    sb[ZZ] = off;
  }
  __syncthreads();
  if (t < ZZ) {
    int run = sb[t];
    for (int b = 0; b < NB; ++b) {
      bbase[b * ZZ + t] = run;
      run += bcnt[b * ZZ + t];
    }
  }
  for (int i = t; i < NT_MAX; i += 256) {
    int base = i * 16, z = -1;
#pragma unroll
    for (int zz = 0; zz < ZZ; ++zz)
      if (base >= sb[zz] && base < sb[zz + 1]) z = zz;
    tspec[i] = z;
  }
}

__global__ __launch_bounds__(256) void k_nfill(const int* __restrict__ species,
                                               const int* __restrict__ bbase,
                                               int* __restrict__ nperm) {
  __shared__ int cur[ZZ];
  int t = threadIdx.x;
  if (t < ZZ) cur[t] = bbase[blockIdx.x * ZZ + t];
  __syncthreads();
  int n = blockIdx.x * 256 + t;
  int pos = atomicAdd(&cur[species[n]], 1);
  nperm[pos] = n;
}

// ---------------------------------------------------------------------------
// linear_up on MFMA (unchanged from round 10).
// ---------------------------------------------------------------------------
__global__ __launch_bounds__(256) void k_up2(
    const float* __restrict__ nf,
    const unsigned short* __restrict__ fragw,
    unsigned short* __restrict__ s_up, unsigned short* __restrict__ v_up) {
  int lane = threadIdx.x & 63;
  int wv = threadIdx.x >> 6;
  int n0 = (blockIdx.x * 4 + wv) * 16;
  int q = lane >> 4, c = lane & 15;
  const f32x4 zero4 = {0.f, 0.f, 0.f, 0.f};
  const float* nrow = nf + (size_t)(n0 + c) * 256;

  f16x8 aS[2], aX[2], aY[2], aZ[2];
#pragma unroll
  for (int ks = 0; ks < 2; ++ks) {
    int k0 = ks * 32 + 8 * q;
    aS[ks] = pack8(*(const float4*)(nrow + k0), *(const float4*)(nrow + k0 + 4));
    float vb[24];
    const float4* vp = (const float4*)(nrow + 64 + 3 * k0);
#pragma unroll
    for (int j = 0; j < 6; ++j) *(float4*)(vb + 4 * j) = vp[j];
#pragma unroll
    for (int i = 0; i < 8; ++i) {
      aX[ks][i] = (f16)vb[3 * i];
      aY[ks][i] = (f16)vb[3 * i + 1];
      aZ[ks][i] = (f16)vb[3 * i + 2];
    }
  }

  f32x4 os[4], ox[4], oy[4], oz[4];
#pragma unroll
  for (int t = 0; t < 4; ++t)
#pragma unroll
    for (int ks = 0; ks < 2; ++ks) {
      f16x8 bS = LDFRAG(252 + t * 2 + ks);
      f16x8 bV = LDFRAG(260 + t * 2 + ks);
      os[t] = __builtin_amdgcn_mfma_f32_16x16x32_f16(aS[ks], bS, ks ? os[t] : zero4, 0, 0, 0);
      ox[t] = __builtin_amdgcn_mfma_f32_16x16x32_f16(aX[ks], bV, ks ? ox[t] : zero4, 0, 0, 0);
      oy[t] = __builtin_amdgcn_mfma_f32_16x16x32_f16(aY[ks], bV, ks ? oy[t] : zero4, 0, 0, 0);
      oz[t] = __builtin_amdgcn_mfma_f32_16x16x32_f16(aZ[ks], bV, ks ? oz[t] : zero4, 0, 0, 0);
    }

#pragma unroll
  for (int t = 0; t < 4; ++t)
#pragma unroll
    for (int r = 0; r < 4; ++r) {
      int n = n0 + 4 * q + r;
      int ch = 16 * t + c;
      s_up[n * 64 + ch] = f2h(os[t][r]);
      v_up[(n * 3 + 0) * 64 + ch] = f2h(ox[t][r]);
      v_up[(n * 3 + 1) * 64 + ch] = f2h(oy[t][r]);
      v_up[(n * 3 + 2) * 64 + ch] = f2h(oz[t][r]);
    }
}

// ---------------------------------------------------------------------------
// Radial MLP + tensor product + scatter, fused. Wave = ONE 16-edge M-tile.
// r15-exact L1..L4 pipeline; each message component atomicAdd'ed into acc
// IMMEDIATELY after computation (no staging registers, no run reduction).
// ---------------------------------------------------------------------------
__global__ __launch_bounds__(256, 4) void k_mlp(
    const float* __restrict__ re, const int* __restrict__ elist,
    const float* __restrict__ vecs, const int* __restrict__ snd,
    const int* __restrict__ rcv,
    const unsigned short* __restrict__ fragw,
    const unsigned short* __restrict__ s_up,
    const unsigned short* __restrict__ v_up,
    float* __restrict__ acc) {
  __shared__ float hs[4][1088];  // [wave][16 rows * 68]
  int lane = threadIdx.x & 63;
  int wv = threadIdx.x >> 6;
  int q = lane >> 4, c = lane & 15;
  int ipb = (blockIdx.x * 4 + wv) * 16;
  float* hw = hs[wv];
  const f32x4 zero4 = {0.f, 0.f, 0.f, 0.f};

  // ---- layer 1 ----
  f16x8 a1 = {0, 0, 0, 0, 0, 0, 0, 0};
  if (q == 0) {
    int e = elist[ipb + c];
    const float4* rp = (const float4*)(re + (size_t)e * 8);
    a1 = pack8(rp[0], rp[1]);
  }
  {
    f32x4 acr[4];
#pragma unroll
    for (int t = 0; t < 4; ++t)
      acr[t] = __builtin_amdgcn_mfma_f32_16x16x32_f16(a1, LDFRAG(t), zero4, 0, 0, 0);
#pragma unroll
    for (int t = 0; t < 4; ++t)
#pragma unroll
      for (int r = 0; r < 4; ++r) {
        float x = silu_f(acr[t][r]);
        hw[(4 * q + r) * 68 + ((16 * t + c) ^ (r << 3))] = x;
      }
  }

  // ---- layers 2 and 3 ----
#pragma unroll
  for (int L = 0; L < 2; ++L) {
    int base = 4 + 8 * L;
    f16x8 af0, af1;
    {
      const float* hp = hw + c * 68 + 8 * (q ^ (c & 3));
      af0 = pack8(*(const float4*)hp, *(const float4*)(hp + 4));
      af1 = pack8(*(const float4*)(hp + 32), *(const float4*)(hp + 36));
    }
    f32x4 acr[4];
#pragma unroll
    for (int t = 0; t < 4; ++t) {
      acr[t] = __builtin_amdgcn_mfma_f32_16x16x32_f16(af0, LDFRAG(base + t * 2), zero4, 0, 0, 0);
      acr[t] = __builtin_amdgcn_mfma_f32_16x16x32_f16(af1, LDFRAG(base + t * 2 + 1), acr[t], 0, 0, 0);
    }
#pragma unroll
    for (int t = 0; t < 4; ++t)
#pragma unroll
      for (int r = 0; r < 4; ++r) {
        float x = silu_f(acr[t][r]);
        hw[(4 * q + r) * 68 + ((16 * t + c) ^ (r << 3))] = x;
      }
  }

  // ---- layer 4 A-fragments (hs read-only from here) ----
  f16x8 a4k0, a4k1;
  {
    const float* hp = hw + c * 68 + 8 * (q ^ (c & 3));
    a4k0 = pack8(*(const float4*)hp, *(const float4*)(hp + 4));
    a4k1 = pack8(*(const float4*)(hp + 32), *(const float4*)(hp + 36));
  }

  // ---- edge geometry + receivers for this lane's 4 rows ----
  int se_[4], rv_[4];
  float Yx[4], Yy[4], Yz[4];
#pragma unroll
  for (int r = 0; r < 4; ++r) {
    int e = elist[ipb + 4 * q + r];
    float ex = vecs[(size_t)e * 3 + 0];
    float ey = vecs[(size_t)e * 3 + 1];
    float ez = vecs[(size_t)e * 3 + 2];
    float rn = 1.0f / (sqrtf(ex * ex + ey * ey + ez * ez) + 1e-9f);
    Yx[r] = ex * rn; Yy[r] = ey * rn; Yz[r] = ez * rn;
    se_[r] = snd[e];
    rv_[r] = rcv[e];
  }

  // ---- layer 4 + TP, two pair-passes; immediate atomic scatter ----
#pragma unroll 1
  for (int pg = 0; pg < 2; ++pg) {
    f16x2 gs[4], gx[4], gy[4], gz[4];
#pragma unroll
    for (int r = 0; r < 4; ++r) {
      const unsigned short* sr = s_up + (size_t)se_[r] * 64 + 4 * c + 2 * pg;
      const unsigned short* vr = v_up + (size_t)se_[r] * 192 + 4 * c + 2 * pg;
      gs[r] = *(const f16x2*)sr;
      gx[r] = *(const f16x2*)vr;
      gy[r] = *(const f16x2*)(vr + 64);
      gz[r] = *(const f16x2*)(vr + 128);
    }
#pragma unroll
    for (int ig2 = 0; ig2 < 2; ++ig2) {
      int ig = 2 * pg + ig2;
      f32x4 o[5];
#pragma unroll
      for (int p = 0; p < 5; ++p) {
        o[p] = __builtin_amdgcn_mfma_f32_16x16x32_f16(
            a4k0, LDFRAG(20 + (ig * 5 + p) * 2 + 0), zero4, 0, 0, 0);
        o[p] = __builtin_amdgcn_mfma_f32_16x16x32_f16(
            a4k1, LDFRAG(20 + (ig * 5 + p) * 2 + 1), o[p], 0, 0, 0);
      }
#pragma unroll
      for (int r = 0; r < 4; ++r) {
        float ss = (float)gs[r][ig2];
        float vx = (float)gx[r][ig2], vy = (float)gy[r][ig2], vz = (float)gz[r][ig2];
        float dt = vx * Yx[r] + vy * Yy[r] + vz * Yz[r];
        float cx = vy * Yz[r] - vz * Yy[r];
        float cy = vz * Yx[r] - vx * Yz[r];
        float cz = vx * Yy[r] - vy * Yx[r];
        float ms = EPS_C * (o[0][r] * ss + o[3][r] * dt);
        float mx = EPS_C * (o[1][r] * Yx[r] + o[2][r] * vx + o[4][r] * (cx * RS2));
        float my = EPS_C * (o[1][r] * Yy[r] + o[2][r] * vy + o[4][r] * (cy * RS2));
        float mz = EPS_C * (o[1][r] * Yz[r] + o[2][r] * vz + o[4][r] * (cz * RS2));
        float* ap = acc + (size_t)rv_[r] * 256 + 4 * c + 2 * pg + ig2;
        atomicAdd(ap, ms);
        atomicAdd(ap + 64, mx);
        atomicAdd(ap + 128, my);
        atomicAdd(ap + 192, mz);
      }
    }
  }
}

// ---------------------------------------------------------------------------
// Post stage on MFMA (unchanged from round 8).
// ---------------------------------------------------------------------------
__global__ __launch_bounds__(128) void k_post2(
    const float* __restrict__ nf, const float* __restrict__ acc,
    const unsigned short* __restrict__ fragw,
    const float* __restrict__ Wsc, const float* __restrict__ Wout,
    const int* __restrict__ nperm, const int* __restrict__ tspec,
    float* __restrict__ out) {
  __shared__ float hs[2][2][1088];
  int lane = threadIdx.x & 63;
  int wv = threadIdx.x >> 6;
  int tt = blockIdx.x * 2 + wv;
  int spec = tspec[tt];
  if (spec < 0) return;
  int q = lane >> 4, c = lane & 15;
  float* hw0 = hs[wv][0];
  float* hw1 = hs[wv][1];
  const f32x4 zero4 = {0.f, 0.f, 0.f, 0.f};

  int nA = nperm[tt * 16 + c];
  size_t rowA = (size_t)((nA < 0) ? 0 : nA);
  const float* arow = acc + rowA * 256;
  const float* nrow = nf + rowA * 256;

  // A-fragments: down (from acc) and skip (from nf)
  f16x8 aS[2], aVX[2], aVY[2], aVZ[2];
  f16x8 kS[2], kX[2], kY[2], kZ[2];
#pragma unroll
  for (int ks = 0; ks < 2; ++ks) {
    int k0 = ks * 32 + 8 * q;
    aS[ks]  = pack8(*(const float4*)(arow + k0),       *(const float4*)(arow + k0 + 4));
    aVX[ks] = pack8(*(const float4*)(arow + 64 + k0),  *(const float4*)(arow + 68 + k0));
    aVY[ks] = pack8(*(const float4*)(arow + 128 + k0), *(const float4*)(arow + 132 + k0));
    aVZ[ks] = pack8(*(const float4*)(arow + 192 + k0), *(const float4*)(arow + 196 + k0));
    kS[ks]  = pack8(*(const float4*)(nrow + k0),       *(const float4*)(nrow + k0 + 4));
    float vb[24];
    const float4* vp = (const float4*)(nrow + 64 + 3 * k0);
#pragma unroll
    for (int j = 0; j < 6; ++j) *(float4*)(vb + 4 * j) = vp[j];
#pragma unroll
    for (int i = 0; i < 8; ++i) {
      kX[ks][i] = (f16)vb[3 * i];
      kY[ks][i] = (f16)vb[3 * i + 1];
      kZ[ks][i] = (f16)vb[3 * i + 2];
    }
  }

  // down linear (INV8 in B)
  f32x4 ds[4], dvx[4], dvy[4], dvz[4];
#pragma unroll
  for (int t = 0; t < 4; ++t)
#pragma unroll
    for (int ks = 0; ks < 2; ++ks) {
      f16x8 bS = LDFRAG(60 + t * 2 + ks);
      f16x8 bV = LDFRAG(68 + t * 2 + ks);
      ds[t]  = __builtin_amdgcn_mfma_f32_16x16x32_f16(aS[ks],  bS, ks ? ds[t]  : zero4, 0, 0, 0);
      dvx[t] = __builtin_amdgcn_mfma_f32_16x16x32_f16(aVX[ks], bV, ks ? dvx[t] : zero4, 0, 0, 0);
      dvy[t] = __builtin_amdgcn_mfma_f32_16x16x32_f16(aVY[ks], bV, ks ? dvy[t] : zero4, 0, 0, 0);
      dvz[t] = __builtin_amdgcn_mfma_f32_16x16x32_f16(aVZ[ks], bV, ks ? dvz[t] : zero4, 0, 0, 0);
    }

  // skip linear (INVZ in B) -> initializes post accumulators
  f32x4 ps[4], pvx[4], pvy[4], pvz[4];
#pragma unroll
  for (int t = 0; t < 4; ++t)
#pragma unroll
    for (int ks = 0; ks < 2; ++ks) {
      f16x8 bs = LDFRAG(92 + spec * 8 + t * 2 + ks);
      f16x8 bv = LDFRAG(172 + spec * 8 + t * 2 + ks);
      ps[t]  = __builtin_amdgcn_mfma_f32_16x16x32_f16(kS[ks], bs, ks ? ps[t]  : zero4, 0, 0, 0);
      pvx[t] = __builtin_amdgcn_mfma_f32_16x16x32_f16(kX[ks], bv, ks ? pvx[t] : zero4, 0, 0, 0);
      pvy[t] = __builtin_amdgcn_mfma_f32_16x16x32_f16(kY[ks], bv, ks ? pvy[t] : zero4, 0, 0, 0);
      pvz[t] = __builtin_amdgcn_mfma_f32_16x16x32_f16(kZ[ks], bv, ks ? pvz[t] : zero4, 0, 0, 0);
    }

  // symmetric contraction, elementwise in C/D layout
  f32x4 so[4], vcm[4];
  const float* wzp = Wsc + spec * 576 + c;
#pragma unroll
  for (int t = 0; t < 4; ++t) {
    int col = 16 * t;
    float w0 = wzp[col], w1 = wzp[64 + col], w2 = wzp[128 + col];
    float w3 = wzp[192 + col], w4 = wzp[256 + col];
    float w5 = wzp[320 + col], w6 = wzp[384 + col];
    float w7 = wzp[448 + col], w8 = wzp[512 + col];
#pragma unroll
    for (int r = 0; r < 4; ++r) {
      float s = ds[t][r];
      float vx = dvx[t][r], vy = dvy[t][r], vz = dvz[t][r];
      float vn2 = vx * vx + vy * vy + vz * vz;
      so[t][r]  = w0 * s + w1 * s * s + w2 * vn2 + w3 * s * s * s + w4 * s * vn2;
      vcm[t][r] = w5 + w6 * s + w7 * s * s + w8 * vn2;
    }
  }

  // post linear pass 1: s_o and vx (INV8 in B)
#pragma unroll
  for (int t = 0; t < 4; ++t)
#pragma unroll
    for (int r = 0; r < 4; ++r) {
      int ad = (4 * q + r) * 68 + ((16 * t + c) ^ (r << 3));
      hw0[ad] = so[t][r];
      hw1[ad] = vcm[t][r] * dvx[t][r];
    }
  {
    f16x8 aP0[2], aP1[2];
#pragma unroll
    for (int ks = 0; ks < 2; ++ks) {
      const float* hp0 = hw0 + c * 68 + ks * 32 + 8 * (q ^ (c & 3));
      const float* hp1 = hw1 + c * 68 + ks * 32 + 8 * (q ^ (c & 3));
      aP0[ks] = pack8(*(const float4*)hp0, *(const float4*)(hp0 + 4));
      aP1[ks] = pack8(*(const float4*)hp1, *(const float4*)(hp1 + 4));
    }
#pragma unroll
    for (int t = 0; t < 4; ++t)
#pragma unroll
      for (int ks = 0; ks < 2; ++ks) {
        ps[t]  = __builtin_amdgcn_mfma_f32_16x16x32_f16(aP0[ks], LDFRAG(76 + t * 2 + ks), ps[t], 0, 0, 0);
        pvx[t] = __builtin_amdgcn_mfma_f32_16x16x32_f16(aP1[ks], LDFRAG(84 + t * 2 + ks), pvx[t], 0, 0, 0);
      }
  }
  // post linear pass 2: vy and vz
#pragma unroll
  for (int t = 0; t < 4; ++t)
#pragma unroll
    for (int r = 0; r < 4; ++r) {
      int ad = (4 * q + r) * 68 + ((16 * t + c) ^ (r << 3));
      hw0[ad] = vcm[t][r] * dvy[t][r];
      hw1[ad] = vcm[t][r] * dvz[t][r];
    }
  {
    f16x8 aP0[2], aP1[2];
#pragma unroll
    for (int ks = 0; ks < 2; ++ks) {
      const float* hp0 = hw0 + c * 68 + ks * 32 + 8 * (q ^ (c & 3));
      const float* hp1 = hw1 + c * 68 + ks * 32 + 8 * (q ^ (c & 3));
      aP0[ks] = pack8(*(const float4*)hp0, *(const float4*)(hp0 + 4));
      aP1[ks] = pack8(*(const float4*)hp1, *(const float4*)(hp1 + 4));
    }
#pragma unroll
    for (int t = 0; t < 4; ++t)
#pragma unroll
      for (int ks = 0; ks < 2; ++ks) {
        pvy[t] = __builtin_amdgcn_mfma_f32_16x16x32_f16(aP0[ks], LDFRAG(84 + t * 2 + ks), pvy[t], 0, 0, 0);
        pvz[t] = __builtin_amdgcn_mfma_f32_16x16x32_f16(aP1[ks], LDFRAG(84 + t * 2 + ks), pvz[t], 0, 0, 0);
      }
  }

  // outputs: features + scalar head
  float wo[4];
#pragma unroll
  for (int t = 0; t < 4; ++t) wo[t] = Wout[16 * t + c];
  int nst[4];
#pragma unroll
  for (int r = 0; r < 4; ++r) nst[r] = nperm[tt * 16 + 4 * q + r];
#pragma unroll
  for (int r = 0; r < 4; ++r) {
    float part = 0.f;
#pragma unroll
    for (int t = 0; t < 4; ++t) part += ps[t][r] * wo[t];
    part += __shfl_xor(part, 1);
    part += __shfl_xor(part, 2);
    part += __shfl_xor(part, 4);
    part += __shfl_xor(part, 8);
    int n = nst[r];
    if (n >= 0) {
      float* orow = out + NN + (size_t)n * 256;
#pragma unroll
      for (int t = 0; t < 4; ++t) {
        int col = 16 * t + c;
        orow[col] = ps[t][r];
        orow[64 + col * 3 + 0] = pvx[t][r];
        orow[64 + col * 3 + 1] = pvy[t][r];
        orow[64 + col * 3 + 2] = pvz[t][r];
      }
      if (c == 0) out[n] = part * INV8;
    }
  }
}

extern "C" void kernel_launch(void* const* d_in, const int* in_sizes, int n_in,
                              void* d_out, int out_size, void* d_ws, size_t ws_size,
                              hipStream_t stream) {
  (void)in_sizes; (void)n_in; (void)out_size; (void)ws_size;
  const float* vecs = (const float*)d_in[0];
  const float* nf   = (const float*)d_in[1];
  const float* re   = (const float*)d_in[2];
  const float* Wsks = (const float*)d_in[3];
  const float* Wskv = (const float*)d_in[4];
  const float* Wups = (const float*)d_in[5];
  const float* Wupv = (const float*)d_in[6];
  const float* W1   = (const float*)d_in[7];
  const float* W2   = (const float*)d_in[8];
  const float* W3   = (const float*)d_in[9];
  const float* W4   = (const float*)d_in[10];
  const float* Wdns = (const float*)d_in[11];
  const float* Wdnv = (const float*)d_in[12];
  const float* Wsc  = (const float*)d_in[13];
  const float* Wpss = (const float*)d_in[14];
  const float* Wpsv = (const float*)d_in[15];
  const float* Wout = (const float*)d_in[16];
  const int* species = (const int*)d_in[17];
  const int* snd     = (const int*)d_in[18];
  const int* rcv     = (const int*)d_in[19];

  float* ws = (float*)d_ws;
  unsigned short* s_up  = (unsigned short*)ws;              // N*64 f16
  unsigned short* v_up  = (unsigned short*)(ws + 1048576);  // N*192 f16
  float* acc   = ws + 4194304;                              // N*256 f32
  unsigned short* fragw = (unsigned short*)(ws + 12582912); // 268 frags
  int* row_st  = (int*)(ws + 12651520);                     // 32832
  int* cursor  = (int*)(ws + 12684352);                     // 32768
  int* elist   = (int*)(ws + 12717120);                     // 262144
  int* nperm   = (int*)(ws + 12979264);                     // 33280
  int* tspec   = (int*)(ws + 13012544);                     // 2304
  int* sbins   = (int*)(ws + 13014848);                     // 64
  int* bcnt    = (int*)(ws + 13014912);                     // 1280
  int* bbase   = (int*)(ws + 13016192);                     // 1280

  hipMemsetAsync(cursor, 0, NN * sizeof(int), stream);
  hipMemsetAsync(acc, 0, (size_t)NN * 256 * sizeof(float), stream);
  hipMemsetAsync(sbins, 0, 64 * sizeof(int), stream);
  hipMemsetAsync(nperm, 0xFF, NT_MAX * 16 * sizeof(int), stream);
  k_frag<<<67, 256, 0, stream>>>(W1, W2, W3, W4, Wdns, Wdnv, Wpss, Wpsv,
                                 Wsks, Wskv, Wups, Wupv, fragw);
  k_hist<<<EE / 256, 256, 0, stream>>>(rcv, cursor);
  k_scan<<<1, 1024, 0, stream>>>(cursor, row_st, cursor);
  k_fill<<<EE / 256, 256, 0, stream>>>(rcv, cursor, elist);
  k_nhist<<<NB, 256, 0, stream>>>(species, sbins, bcnt);
  k_nscan<<<1, 256, 0, stream>>>(sbins, bcnt, bbase, tspec);
  k_nfill<<<NB, 256, 0, stream>>>(species, bbase, nperm);
  k_up2<<<512, 256, 0, stream>>>(nf, fragw, s_up, v_up);
  k_mlp<<<EE / 64, 256, 0, stream>>>(re, elist, vecs, snd, rcv, fragw,
                                     s_up, v_up, acc);
  k_post2<<<NT_MAX / 2, 128, 0, stream>>>(nf, acc, fragw, Wsc, Wout,
                                          nperm, tspec, (float*)d_out);
}

// Round 12
// 353.192 us; speedup vs baseline: 3.3053x; 3.3053x over previous
//
#include <hip/hip_runtime.h>
#include <math.h>

// ---------------------------------------------------------------------------
// MACE layer, round 18: r15 base (last good, 362.6us) + k_gather tweaks.
//  - r17 result: immediate-atomic scatter is CORRECT (buffering diagnosis
//    confirmed, 7/7) but atomic-throughput-bound (67M atomics = 950us,
//    WRITE 1.09GB). Atomic scatter abandoned; wm round-trip retained.
//  - k_gather: lane g reads ONE contiguous uint2 (shorts 4g..4g+3) per edge
//    (was 2x4B); covered channels {4cc+2pg,+1,4cc+4+2pg,+1}, cc=2(g&7),
//    pg=(g&15)>>3 (bijective over 0..63); acc store = two float2.
//  - Chunk 0 stores (no RMW, no early return) -> acc memset and chunk-0
//    acc read deleted.
//  - Everything else byte-identical to round 15.
//
// Workspace (floats, ~116 MB):
//   s_up   [N*64  f16]  @ 0
//   v_up   [N*192 f16]  @ 1048576
//   acc    [N*256 f32]  @ 4194304   (initialized by chunk-0 k_gather)
//   fragw  [268 frags]  @ 12582912  (68608-f slot)
//   row_st [32832 int]  @ 12651520
//   cursor [32768 int]  @ 12684352
//   elist  [262144 int] @ 12717120
//   nperm  [33280 int]  @ 12979264  (memset -1)
//   tspec  [2304 int]   @ 13012544
//   sbins  [64 int]     @ 13014848
//   bcnt   [1280 int]   @ 13014912
//   bbase  [1280 int]   @ 13016192
//   wm     [EC*256 bf16]@ 13017472  (64 MB message buffer, permuted rows)
// ---------------------------------------------------------------------------

#define NN 32768
#define EE 262144
#define EC 131072                        // edges per chunk (2 chunks)
#define ZZ 10
#define NB 128                           // NN/256 blocks for binning
#define NT_MAX 2064                      // >= ceil((NN + ZZ*15)/16), even
#define INV8 0.125f                      // 1/sqrt(64)
#define INV_SQRT8 0.35355339059327373f   // 1/sqrt(8)
#define INVZ 0.039528470752104741f       // 1/sqrt(64*10)
#define EPS_C 0.25f
#define RS2 0.70710678118654752f         // 1/sqrt(2)

typedef _Float16 f16;
typedef f16 f16x8 __attribute__((ext_vector_type(8)));
typedef f16 f16x4 __attribute__((ext_vector_type(4)));
typedef f16 f16x2 __attribute__((ext_vector_type(2)));
typedef float f32x4 __attribute__((ext_vector_type(4)));

#define LDFRAG(fid) (*(const f16x8*)(fragw + ((size_t)(fid) << 9) + (lane << 3)))

__device__ __forceinline__ unsigned bfpair(float lo, float hi) {
  unsigned ul = __float_as_uint(lo);
  unsigned uh = __float_as_uint(hi);
  ul = (ul + 0x7FFFu + ((ul >> 16) & 1u)) >> 16;
  uh = (uh + 0x7FFFu + ((uh >> 16) & 1u)) >> 16;
  return ul | (uh << 16);
}

__device__ __forceinline__ unsigned short f2h(float x) {
  union { f16 h; unsigned short u; } cv;
  cv.h = (f16)x;
  return cv.u;
}

__device__ __forceinline__ f16x8 pack8(float4 a, float4 b) {
  f16x8 r;
  r[0] = (f16)a.x; r[1] = (f16)a.y; r[2] = (f16)a.z; r[3] = (f16)a.w;
  r[4] = (f16)b.x; r[5] = (f16)b.y; r[6] = (f16)b.z; r[7] = (f16)b.w;
  return r;
}

__device__ __forceinline__ float silu_f(float x) {
  return x / (1.0f + __expf(-x));
}

// ---------------------------------------------------------------------------
// Weight fragment packing (unchanged from round 15).
// ---------------------------------------------------------------------------
__global__ __launch_bounds__(256) void k_frag(
    const float* __restrict__ W1, const float* __restrict__ W2,
    const float* __restrict__ W3, const float* __restrict__ W4,
    const float* __restrict__ Wdns, const float* __restrict__ Wdnv,
    const float* __restrict__ Wpss, const float* __restrict__ Wpsv,
    const float* __restrict__ Wsks, const float* __restrict__ Wskv,
    const float* __restrict__ Wups, const float* __restrict__ Wupv,
    unsigned short* __restrict__ fragw) {
  int id = blockIdx.x * 256 + threadIdx.x;
  if (id >= 268 * 64) return;
  int fid = id >> 6, lane = id & 63;
  int q = lane >> 4, c = lane & 15;
  const float* W; int K = 64, N = 64, t, ks; float sc; int w4 = 0;
  if (fid < 4)       { W = W1; K = 8; N = 64; t = fid; ks = 0; sc = INV_SQRT8; }
  else if (fid < 12) { W = W2; t = (fid - 4) >> 1;  ks = (fid - 4) & 1;  sc = INV8; }
  else if (fid < 20) { W = W3; t = (fid - 12) >> 1; ks = (fid - 12) & 1; sc = INV8; }
  else if (fid < 60) { W = W4; N = 320; t = (fid - 20) >> 1; ks = (fid - 20) & 1; sc = INV8; w4 = 1; }
  else {
    int f2 = fid - 60; sc = INV8;
    if (f2 < 8)        { W = Wdns; }
    else if (f2 < 16)  { W = Wdnv; f2 -= 8; }
    else if (f2 < 24)  { W = Wpss; f2 -= 16; }
    else if (f2 < 32)  { W = Wpsv; f2 -= 24; }
    else if (f2 < 112) { f2 -= 32; W = Wsks + (f2 >> 3) * 4096; f2 &= 7; sc = INVZ; }
    else if (f2 < 192) { f2 -= 112; W = Wskv + (f2 >> 3) * 4096; f2 &= 7; sc = INVZ; }
    else if (f2 < 200) { W = Wups; f2 -= 192; }
    else               { W = Wupv; f2 -= 200; }
    t = f2 >> 1; ks = f2 & 1;
  }
  int col = w4 ? ((t % 5) * 64 + 4 * c + (t / 5)) : (t * 16 + c);
  unsigned short o[8];
#pragma unroll
  for (int i = 0; i < 8; ++i) {
    int k = ks * 32 + 8 * q + i;
    float v = (k < K) ? W[k * N + col] * sc : 0.0f;
    o[i] = f2h(v);
  }
  *(uint4*)(fragw + (size_t)id * 8) = *(const uint4*)o;
}

__global__ __launch_bounds__(256) void k_hist(const int* __restrict__ rcv,
                                              int* __restrict__ cnt) {
  int e = blockIdx.x * 256 + threadIdx.x;
  atomicAdd(&cnt[rcv[e]], 1);
}

__global__ __launch_bounds__(1024) void k_scan(const int* __restrict__ cnt,
                                               int* __restrict__ row_start,
                                               int* __restrict__ cursor) {
  __shared__ int tot[1024];
  int t = threadIdx.x;
  int base = t * 32;
  int local[32];
  int s = 0;
#pragma unroll
  for (int i = 0; i < 32; ++i) { local[i] = s; s += cnt[base + i]; }
  tot[t] = s;
  __syncthreads();
  for (int off = 1; off < 1024; off <<= 1) {
    int v = (t >= off) ? tot[t - off] : 0;
    __syncthreads();
    tot[t] += v;
    __syncthreads();
  }
  int prefix = (t == 0) ? 0 : tot[t - 1];
#pragma unroll
  for (int i = 0; i < 32; ++i) {
    int v = prefix + local[i];
    row_start[base + i] = v;
    cursor[base + i] = v;
  }
  if (t == 1023) row_start[NN] = prefix + s;
}

__global__ __launch_bounds__(256) void k_fill(const int* __restrict__ rcv,
                                              int* __restrict__ cursor,
                                              int* __restrict__ elist) {
  int e = blockIdx.x * 256 + threadIdx.x;
  int pos = atomicAdd(&cursor[rcv[e]], 1);
  elist[pos] = e;
}

// ---- node species binning, hierarchical (unchanged) ----
__global__ __launch_bounds__(256) void k_nhist(const int* __restrict__ species,
                                               int* __restrict__ sbins,
                                               int* __restrict__ bcnt) {
  __shared__ int h[ZZ];
  int t = threadIdx.x;
  if (t < ZZ) h[t] = 0;
  __syncthreads();
  int n = blockIdx.x * 256 + t;
  atomicAdd(&h[species[n]], 1);
  __syncthreads();
  if (t < ZZ) {
    bcnt[blockIdx.x * ZZ + t] = h[t];
    atomicAdd(&sbins[32 + t], h[t]);
  }
}

__global__ __launch_bounds__(256) void k_nscan(int* __restrict__ sbins,
                                               const int* __restrict__ bcnt,
                                               int* __restrict__ bbase,
                                               int* __restrict__ tspec) {
  __shared__ int sb[12];
  int t = threadIdx.x;
  if (t == 0) {
    int off = 0;
    for (int z = 0; z < ZZ; ++z) {
      sb[z] = off;
      off += ((sbins[32 + z] + 15) >> 4) << 4;
    }
    sb[ZZ] = off;
  }
  __syncthreads();
  if (t < ZZ) {
    int run = sb[t];
    for (int b = 0; b < NB; ++b) {
      bbase[b * ZZ + t] = run;
      run += bcnt[b * ZZ + t];
    }
  }
  for (int i = t; i < NT_MAX; i += 256) {
    int base = i * 16, z = -1;
#pragma unroll
    for (int zz = 0; zz < ZZ; ++zz)
      if (base >= sb[zz] && base < sb[zz + 1]) z = zz;
    tspec[i] = z;
  }
}

__global__ __launch_bounds__(256) void k_nfill(const int* __restrict__ species,
                                               const int* __restrict__ bbase,
                                               int* __restrict__ nperm) {
  __shared__ int cur[ZZ];
  int t = threadIdx.x;
  if (t < ZZ) cur[t] = bbase[blockIdx.x * ZZ + t];
  __syncthreads();
  int n = blockIdx.x * 256 + t;
  int pos = atomicAdd(&cur[species[n]], 1);
  nperm[pos] = n;
}

// ---------------------------------------------------------------------------
// linear_up on MFMA (unchanged from round 10).
// ---------------------------------------------------------------------------
__global__ __launch_bounds__(256) void k_up2(
    const float* __restrict__ nf,
    const unsigned short* __restrict__ fragw,
    unsigned short* __restrict__ s_up, unsigned short* __restrict__ v_up) {
  int lane = threadIdx.x & 63;
  int wv = threadIdx.x >> 6;
  int n0 = (blockIdx.x * 4 + wv) * 16;
  int q = lane >> 4, c = lane & 15;
  const f32x4 zero4 = {0.f, 0.f, 0.f, 0.f};
  const float* nrow = nf + (size_t)(n0 + c) * 256;

  f16x8 aS[2], aX[2], aY[2], aZ[2];
#pragma unroll
  for (int ks = 0; ks < 2; ++ks) {
    int k0 = ks * 32 + 8 * q;
    aS[ks] = pack8(*(const float4*)(nrow + k0), *(const float4*)(nrow + k0 + 4));
    float vb[24];
    const float4* vp = (const float4*)(nrow + 64 + 3 * k0);
#pragma unroll
    for (int j = 0; j < 6; ++j) *(float4*)(vb + 4 * j) = vp[j];
#pragma unroll
    for (int i = 0; i < 8; ++i) {
      aX[ks][i] = (f16)vb[3 * i];
      aY[ks][i] = (f16)vb[3 * i + 1];
      aZ[ks][i] = (f16)vb[3 * i + 2];
    }
  }

  f32x4 os[4], ox[4], oy[4], oz[4];
#pragma unroll
  for (int t = 0; t < 4; ++t)
#pragma unroll
    for (int ks = 0; ks < 2; ++ks) {
      f16x8 bS = LDFRAG(252 + t * 2 + ks);
      f16x8 bV = LDFRAG(260 + t * 2 + ks);
      os[t] = __builtin_amdgcn_mfma_f32_16x16x32_f16(aS[ks], bS, ks ? os[t] : zero4, 0, 0, 0);
      ox[t] = __builtin_amdgcn_mfma_f32_16x16x32_f16(aX[ks], bV, ks ? ox[t] : zero4, 0, 0, 0);
      oy[t] = __builtin_amdgcn_mfma_f32_16x16x32_f16(aY[ks], bV, ks ? oy[t] : zero4, 0, 0, 0);
      oz[t] = __builtin_amdgcn_mfma_f32_16x16x32_f16(aZ[ks], bV, ks ? oz[t] : zero4, 0, 0, 0);
    }

#pragma unroll
  for (int t = 0; t < 4; ++t)
#pragma unroll
    for (int r = 0; r < 4; ++r) {
      int n = n0 + 4 * q + r;
      int ch = 16 * t + c;
      s_up[n * 64 + ch] = f2h(os[t][r]);
      v_up[(n * 3 + 0) * 64 + ch] = f2h(ox[t][r]);
      v_up[(n * 3 + 1) * 64 + ch] = f2h(oy[t][r]);
      v_up[(n * 3 + 2) * 64 + ch] = f2h(oz[t][r]);
    }
}

// ---------------------------------------------------------------------------
// Radial MLP + tensor product, fused (byte-identical to round 15).
// ---------------------------------------------------------------------------
__global__ __launch_bounds__(256, 4) void k_mlp(
    const float* __restrict__ re, const int* __restrict__ elist,
    const float* __restrict__ vecs, const int* __restrict__ snd,
    const unsigned short* __restrict__ fragw,
    const unsigned short* __restrict__ s_up,
    const unsigned short* __restrict__ v_up,
    unsigned short* __restrict__ wm, int ip0) {
  __shared__ float hs[4][1088];  // [wave][16 rows * 68]
  int lane = threadIdx.x & 63;
  int wv = threadIdx.x >> 6;
  int q = lane >> 4, c = lane & 15;
  int ipb = ip0 + (blockIdx.x * 4 + wv) * 16;
  float* hw = hs[wv];
  const f32x4 zero4 = {0.f, 0.f, 0.f, 0.f};

  // ---- layer 1 ----
  f16x8 a1 = {0, 0, 0, 0, 0, 0, 0, 0};
  if (q == 0) {
    int e = elist[ipb + c];
    const float4* rp = (const float4*)(re + (size_t)e * 8);
    a1 = pack8(rp[0], rp[1]);
  }
  {
    f32x4 acc[4];
#pragma unroll
    for (int t = 0; t < 4; ++t)
      acc[t] = __builtin_amdgcn_mfma_f32_16x16x32_f16(a1, LDFRAG(t), zero4, 0, 0, 0);
#pragma unroll
    for (int t = 0; t < 4; ++t)
#pragma unroll
      for (int r = 0; r < 4; ++r) {
        float x = silu_f(acc[t][r]);
        hw[(4 * q + r) * 68 + ((16 * t + c) ^ (r << 3))] = x;
      }
  }

  // ---- layers 2 and 3 ----
#pragma unroll
  for (int L = 0; L < 2; ++L) {
    int base = 4 + 8 * L;
    f16x8 af0, af1;
    {
      const float* hp = hw + c * 68 + 8 * (q ^ (c & 3));
      af0 = pack8(*(const float4*)hp, *(const float4*)(hp + 4));
      af1 = pack8(*(const float4*)(hp + 32), *(const float4*)(hp + 36));
    }
    f32x4 acc[4];
#pragma unroll
    for (int t = 0; t < 4; ++t) {
      acc[t] = __builtin_amdgcn_mfma_f32_16x16x32_f16(af0, LDFRAG(base + t * 2), zero4, 0, 0, 0);
      acc[t] = __builtin_amdgcn_mfma_f32_16x16x32_f16(af1, LDFRAG(base + t * 2 + 1), acc[t], 0, 0, 0);
    }
#pragma unroll
    for (int t = 0; t < 4; ++t)
#pragma unroll
      for (int r = 0; r < 4; ++r) {
        float x = silu_f(acc[t][r]);
        hw[(4 * q + r) * 68 + ((16 * t + c) ^ (r << 3))] = x;
      }
  }

  // ---- layer 4 A-fragments (hs read-only from here) ----
  f16x8 a4k0, a4k1;
  {
    const float* hp = hw + c * 68 + 8 * (q ^ (c & 3));
    a4k0 = pack8(*(const float4*)hp, *(const float4*)(hp + 4));
    a4k1 = pack8(*(const float4*)(hp + 32), *(const float4*)(hp + 36));
  }

  // ---- edge geometry for this lane's 4 rows ----
  int se_[4];
  float Yx[4], Yy[4], Yz[4];
#pragma unroll
  for (int r = 0; r < 4; ++r) {
    int e = elist[ipb + 4 * q + r];
    float ex = vecs[(size_t)e * 3 + 0];
    float ey = vecs[(size_t)e * 3 + 1];
    float ez = vecs[(size_t)e * 3 + 2];
    float rn = 1.0f / (sqrtf(ex * ex + ey * ey + ez * ez) + 1e-9f);
    Yx[r] = ex * rn; Yy[r] = ey * rn; Yz[r] = ez * rn;
    se_[r] = snd[e];
  }

  // ---- layer 4 + TP, two pair-passes (channels 4c+2pg, 4c+2pg+1) ----
  size_t orow = (size_t)(ipb - ip0);
#pragma unroll 1
  for (int pg = 0; pg < 2; ++pg) {
    f16x2 gs[4], gx[4], gy[4], gz[4];
#pragma unroll
    for (int r = 0; r < 4; ++r) {
      const unsigned short* sr = s_up + (size_t)se_[r] * 64 + 4 * c + 2 * pg;
      const unsigned short* vr = v_up + (size_t)se_[r] * 192 + 4 * c + 2 * pg;
      gs[r] = *(const f16x2*)sr;
      gx[r] = *(const f16x2*)vr;
      gy[r] = *(const f16x2*)(vr + 64);
      gz[r] = *(const f16x2*)(vr + 128);
    }
    float pms[4], pmx[4], pmy[4], pmz[4];
#pragma unroll
    for (int ig2 = 0; ig2 < 2; ++ig2) {
      int ig = 2 * pg + ig2;
      f32x4 o[5];
#pragma unroll
      for (int p = 0; p < 5; ++p) {
        o[p] = __builtin_amdgcn_mfma_f32_16x16x32_f16(
            a4k0, LDFRAG(20 + (ig * 5 + p) * 2 + 0), zero4, 0, 0, 0);
        o[p] = __builtin_amdgcn_mfma_f32_16x16x32_f16(
            a4k1, LDFRAG(20 + (ig * 5 + p) * 2 + 1), o[p], 0, 0, 0);
      }
#pragma unroll
      for (int r = 0; r < 4; ++r) {
        float ss = (float)gs[r][ig2];
        float vx = (float)gx[r][ig2], vy = (float)gy[r][ig2], vz = (float)gz[r][ig2];
        float dt = vx * Yx[r] + vy * Yy[r] + vz * Yz[r];
        float cx = vy * Yz[r] - vz * Yy[r];
        float cy = vz * Yx[r] - vx * Yz[r];
        float cz = vx * Yy[r] - vy * Yx[r];
        float ms = EPS_C * (o[0][r] * ss + o[3][r] * dt);
        float mx = EPS_C * (o[1][r] * Yx[r] + o[2][r] * vx + o[4][r] * (cx * RS2));
        float my = EPS_C * (o[1][r] * Yy[r] + o[2][r] * vy + o[4][r] * (cy * RS2));
        float mz = EPS_C * (o[1][r] * Yz[r] + o[2][r] * vz + o[4][r] * (cz * RS2));
        if (ig2 == 0) {
          pms[r] = ms; pmx[r] = mx; pmy[r] = my; pmz[r] = mz;
        } else {
          // permuted layout: short off = comp*64 + pg*32 + 2c (low = even ch)
          unsigned short* wr = wm + (orow + 4 * q + r) * 256 + pg * 32 + 2 * c;
          *(unsigned*)(wr)       = bfpair(pms[r], ms);
          *(unsigned*)(wr + 64)  = bfpair(pmx[r], mx);
          *(unsigned*)(wr + 128) = bfpair(pmy[r], my);
          *(unsigned*)(wr + 192) = bfpair(pmz[r], mz);
        }
      }
    }
  }
}

// one wave per node; contiguous clipped CSR range [lo,hi). Lane g reads one
// contiguous uint2 (shorts 4g..4g+3 of the permuted row): comp = g>>4,
// pg = (g&15)>>3, cc = 2*(g&7) -> channels {4cc+2pg, +1, 4cc+4+2pg, +1};
// acc store = two float2 at comp*64+4cc+2pg and +4. Chunk 0 (e0==0) stores
// unconditionally (initializes acc; no memset, no RMW read).
__global__ __launch_bounds__(256) void k_gather(
    const unsigned short* __restrict__ m_buf,
    const int* __restrict__ row_start,
    float* __restrict__ acc, int e0, int e1) {
  int g = threadIdx.x & 63;
  int wv = threadIdx.x >> 6;
  int n = blockIdx.x * 4 + wv;
  int beg = row_start[n], end = row_start[n + 1];
  int lo = beg > e0 ? beg : e0;
  int hi = end < e1 ? end : e1;
  if (e0 > 0 && lo >= hi) return;
  float2 a0 = make_float2(0.f, 0.f);
  float2 a1 = make_float2(0.f, 0.f);
  for (int i = lo; i < hi; ++i) {
    uint2 m = *(const uint2*)(m_buf + (size_t)(i - e0) * 256 + g * 4);
    a0.x += __uint_as_float(m.x << 16);
    a0.y += __uint_as_float(m.x & 0xFFFF0000u);
    a1.x += __uint_as_float(m.y << 16);
    a1.y += __uint_as_float(m.y & 0xFFFF0000u);
  }
  int comp = g >> 4;
  int pg = (g & 15) >> 3;
  int cc = 2 * (g & 7);
  float* d0 = acc + (size_t)n * 256 + comp * 64 + 4 * cc + 2 * pg;
  float* d1 = d0 + 4;
  if (e0 == 0) {
    *(float2*)d0 = a0;
    *(float2*)d1 = a1;
  } else {
    float2 p0 = *(const float2*)d0;
    float2 p1 = *(const float2*)d1;
    *(float2*)d0 = make_float2(a0.x + p0.x, a0.y + p0.y);
    *(float2*)d1 = make_float2(a1.x + p1.x, a1.y + p1.y);
  }
}

// ---------------------------------------------------------------------------
// Post stage on MFMA (unchanged from round 8).
// ---------------------------------------------------------------------------
__global__ __launch_bounds__(128) void k_post2(
    const float* __restrict__ nf, const float* __restrict__ acc,
    const unsigned short* __restrict__ fragw,
    const float* __restrict__ Wsc, const float* __restrict__ Wout,
    const int* __restrict__ nperm, const int* __restrict__ tspec,
    float* __restrict__ out) {
  __shared__ float hs[2][2][1088];
  int lane = threadIdx.x & 63;
  int wv = threadIdx.x >> 6;
  int tt = blockIdx.x * 2 + wv;
  int spec = tspec[tt];
  if (spec < 0) return;
  int q = lane >> 4, c = lane & 15;
  float* hw0 = hs[wv][0];
  float* hw1 = hs[wv][1];
  const f32x4 zero4 = {0.f, 0.f, 0.f, 0.f};

  int nA = nperm[tt * 16 + c];
  size_t rowA = (size_t)((nA < 0) ? 0 : nA);
  const float* arow = acc + rowA * 256;
  const float* nrow = nf + rowA * 256;

  // A-fragments: down (from acc) and skip (from nf)
  f16x8 aS[2], aVX[2], aVY[2], aVZ[2];
  f16x8 kS[2], kX[2], kY[2], kZ[2];
#pragma unroll
  for (int ks = 0; ks < 2; ++ks) {
    int k0 = ks * 32 + 8 * q;
    aS[ks]  = pack8(*(const float4*)(arow + k0),       *(const float4*)(arow + k0 + 4));
    aVX[ks] = pack8(*(const float4*)(arow + 64 + k0),  *(const float4*)(arow + 68 + k0));
    aVY[ks] = pack8(*(const float4*)(arow + 128 + k0), *(const float4*)(arow + 132 + k0));
    aVZ[ks] = pack8(*(const float4*)(arow + 192 + k0), *(const float4*)(arow + 196 + k0));
    kS[ks]  = pack8(*(const float4*)(nrow + k0),       *(const float4*)(nrow + k0 + 4));
    float vb[24];
    const float4* vp = (const float4*)(nrow + 64 + 3 * k0);
#pragma unroll
    for (int j = 0; j < 6; ++j) *(float4*)(vb + 4 * j) = vp[j];
#pragma unroll
    for (int i = 0; i < 8; ++i) {
      kX[ks][i] = (f16)vb[3 * i];
      kY[ks][i] = (f16)vb[3 * i + 1];
      kZ[ks][i] = (f16)vb[3 * i + 2];
    }
  }

  // down linear (INV8 in B)
  f32x4 ds[4], dvx[4], dvy[4], dvz[4];
#pragma unroll
  for (int t = 0; t < 4; ++t)
#pragma unroll
    for (int ks = 0; ks < 2; ++ks) {
      f16x8 bS = LDFRAG(60 + t * 2 + ks);
      f16x8 bV = LDFRAG(68 + t * 2 + ks);
      ds[t]  = __builtin_amdgcn_mfma_f32_16x16x32_f16(aS[ks],  bS, ks ? ds[t]  : zero4, 0, 0, 0);
      dvx[t] = __builtin_amdgcn_mfma_f32_16x16x32_f16(aVX[ks], bV, ks ? dvx[t] : zero4, 0, 0, 0);
      dvy[t] = __builtin_amdgcn_mfma_f32_16x16x32_f16(aVY[ks], bV, ks ? dvy[t] : zero4, 0, 0, 0);
      dvz[t] = __builtin_amdgcn_mfma_f32_16x16x32_f16(aVZ[ks], bV, ks ? dvz[t] : zero4, 0, 0, 0);
    }

  // skip linear (INVZ in B) -> initializes post accumulators
  f32x4 ps[4], pvx[4], pvy[4], pvz[4];
#pragma unroll
  for (int t = 0; t < 4; ++t)
#pragma unroll
    for (int ks = 0; ks < 2; ++ks) {
      f16x8 bs = LDFRAG(92 + spec * 8 + t * 2 + ks);
      f16x8 bv = LDFRAG(172 + spec * 8 + t * 2 + ks);
      ps[t]  = __builtin_amdgcn_mfma_f32_16x16x32_f16(kS[ks], bs, ks ? ps[t]  : zero4, 0, 0, 0);
      pvx[t] = __builtin_amdgcn_mfma_f32_16x16x32_f16(kX[ks], bv, ks ? pvx[t] : zero4, 0, 0, 0);
      pvy[t] = __builtin_amdgcn_mfma_f32_16x16x32_f16(kY[ks], bv, ks ? pvy[t] : zero4, 0, 0, 0);
      pvz[t] = __builtin_amdgcn_mfma_f32_16x16x32_f16(kZ[ks], bv, ks ? pvz[t] : zero4, 0, 0, 0);
    }

  // symmetric contraction, elementwise in C/D layout
  f32x4 so[4], vcm[4];
  const float* wzp = Wsc + spec * 576 + c;
#pragma unroll
  for (int t = 0; t < 4; ++t) {
    int col = 16 * t;
    float w0 = wzp[col], w1 = wzp[64 + col], w2 = wzp[128 + col];
    float w3 = wzp[192 + col], w4 = wzp[256 + col];
    float w5 = wzp[320 + col], w6 = wzp[384 + col];
    float w7 = wzp[448 + col], w8 = wzp[512 + col];
#pragma unroll
    for (int r = 0; r < 4; ++r) {
      float s = ds[t][r];
      float vx = dvx[t][r], vy = dvy[t][r], vz = dvz[t][r];
      float vn2 = vx * vx + vy * vy + vz * vz;
      so[t][r]  = w0 * s + w1 * s * s + w2 * vn2 + w3 * s * s * s + w4 * s * vn2;
      vcm[t][r] = w5 + w6 * s + w7 * s * s + w8 * vn2;
    }
  }

  // post linear pass 1: s_o and vx (INV8 in B)
#pragma unroll
  for (int t = 0; t < 4; ++t)
#pragma unroll
    for (int r = 0; r < 4; ++r) {
      int ad = (4 * q + r) * 68 + ((16 * t + c) ^ (r << 3));
      hw0[ad] = so[t][r];
      hw1[ad] = vcm[t][r] * dvx[t][r];
    }
  {
    f16x8 aP0[2], aP1[2];
#pragma unroll
    for (int ks = 0; ks < 2; ++ks) {
      const float* hp0 = hw0 + c * 68 + ks * 32 + 8 * (q ^ (c & 3));
      const float* hp1 = hw1 + c * 68 + ks * 32 + 8 * (q ^ (c & 3));
      aP0[ks] = pack8(*(const float4*)hp0, *(const float4*)(hp0 + 4));
      aP1[ks] = pack8(*(const float4*)hp1, *(const float4*)(hp1 + 4));
    }
#pragma unroll
    for (int t = 0; t < 4; ++t)
#pragma unroll
      for (int ks = 0; ks < 2; ++ks) {
        ps[t]  = __builtin_amdgcn_mfma_f32_16x16x32_f16(aP0[ks], LDFRAG(76 + t * 2 + ks), ps[t], 0, 0, 0);
        pvx[t] = __builtin_amdgcn_mfma_f32_16x16x32_f16(aP1[ks], LDFRAG(84 + t * 2 + ks), pvx[t], 0, 0, 0);
      }
  }
  // post linear pass 2: vy and vz
#pragma unroll
  for (int t = 0; t < 4; ++t)
#pragma unroll
    for (int r = 0; r < 4; ++r) {
      int ad = (4 * q + r) * 68 + ((16 * t + c) ^ (r << 3));
      hw0[ad] = vcm[t][r] * dvy[t][r];
      hw1[ad] = vcm[t][r] * dvz[t][r];
    }
  {
    f16x8 aP0[2], aP1[2];
#pragma unroll
    for (int ks = 0; ks < 2; ++ks) {
      const float* hp0 = hw0 + c * 68 + ks * 32 + 8 * (q ^ (c & 3));
      const float* hp1 = hw1 + c * 68 + ks * 32 + 8 * (q ^ (c & 3));
      aP0[ks] = pack8(*(const float4*)hp0, *(const float4*)(hp0 + 4));
      aP1[ks] = pack8(*(const float4*)hp1, *(const float4*)(hp1 + 4));
    }
#pragma unroll
    for (int t = 0; t < 4; ++t)
#pragma unroll
      for (int ks = 0; ks < 2; ++ks) {
        pvy[t] = __builtin_amdgcn_mfma_f32_16x16x32_f16(aP0[ks], LDFRAG(84 + t * 2 + ks), pvy[t], 0, 0, 0);
        pvz[t] = __builtin_amdgcn_mfma_f32_16x16x32_f16(aP1[ks], LDFRAG(84 + t * 2 + ks), pvz[t], 0, 0, 0);
      }
  }

  // outputs: features + scalar head
  float wo[4];
#pragma unroll
  for (int t = 0; t < 4; ++t) wo[t] = Wout[16 * t + c];
  int nst[4];
#pragma unroll
  for (int r = 0; r < 4; ++r) nst[r] = nperm[tt * 16 + 4 * q + r];
#pragma unroll
  for (int r = 0; r < 4; ++r) {
    float part = 0.f;
#pragma unroll
    for (int t = 0; t < 4; ++t) part += ps[t][r] * wo[t];
    part += __shfl_xor(part, 1);
    part += __shfl_xor(part, 2);
    part += __shfl_xor(part, 4);
    part += __shfl_xor(part, 8);
    int n = nst[r];
    if (n >= 0) {
      float* orow = out + NN + (size_t)n * 256;
#pragma unroll
      for (int t = 0; t < 4; ++t) {
        int col = 16 * t + c;
        orow[col] = ps[t][r];
        orow[64 + col * 3 + 0] = pvx[t][r];
        orow[64 + col * 3 + 1] = pvy[t][r];
        orow[64 + col * 3 + 2] = pvz[t][r];
      }
      if (c == 0) out[n] = part * INV8;
    }
  }
}

extern "C" void kernel_launch(void* const* d_in, const int* in_sizes, int n_in,
                              void* d_out, int out_size, void* d_ws, size_t ws_size,
                              hipStream_t stream) {
  (void)in_sizes; (void)n_in; (void)out_size; (void)ws_size;
  const float* vecs = (const float*)d_in[0];
  const float* nf   = (const float*)d_in[1];
  const float* re   = (const float*)d_in[2];
  const float* Wsks = (const float*)d_in[3];
  const float* Wskv = (const float*)d_in[4];
  const float* Wups = (const float*)d_in[5];
  const float* Wupv = (const float*)d_in[6];
  const float* W1   = (const float*)d_in[7];
  const float* W2   = (const float*)d_in[8];
  const float* W3   = (const float*)d_in[9];
  const float* W4   = (const float*)d_in[10];
  const float* Wdns = (const float*)d_in[11];
  const float* Wdnv = (const float*)d_in[12];
  const float* Wsc  = (const float*)d_in[13];
  const float* Wpss = (const float*)d_in[14];
  const float* Wpsv = (const float*)d_in[15];
  const float* Wout = (const float*)d_in[16];
  const int* species = (const int*)d_in[17];
  const int* snd     = (const int*)d_in[18];
  const int* rcv     = (const int*)d_in[19];

  float* ws = (float*)d_ws;
  unsigned short* s_up  = (unsigned short*)ws;              // N*64 f16
  unsigned short* v_up  = (unsigned short*)(ws + 1048576);  // N*192 f16
  float* acc   = ws + 4194304;                              // N*256 f32
  unsigned short* fragw = (unsigned short*)(ws + 12582912); // 268 frags
  int* row_st  = (int*)(ws + 12651520);                     // 32832
  int* cursor  = (int*)(ws + 12684352);                     // 32768
  int* elist   = (int*)(ws + 12717120);                     // 262144
  int* nperm   = (int*)(ws + 12979264);                     // 33280
  int* tspec   = (int*)(ws + 13012544);                     // 2304
  int* sbins   = (int*)(ws + 13014848);                     // 64
  int* bcnt    = (int*)(ws + 13014912);                     // 1280
  int* bbase   = (int*)(ws + 13016192);                     // 1280
  unsigned short* wm = (unsigned short*)(ws + 13017472);    // EC*256 bf16

  hipMemsetAsync(cursor, 0, NN * sizeof(int), stream);
  hipMemsetAsync(sbins, 0, 64 * sizeof(int), stream);
  hipMemsetAsync(nperm, 0xFF, NT_MAX * 16 * sizeof(int), stream);
  k_frag<<<67, 256, 0, stream>>>(W1, W2, W3, W4, Wdns, Wdnv, Wpss, Wpsv,
                                 Wsks, Wskv, Wups, Wupv, fragw);
  k_hist<<<EE / 256, 256, 0, stream>>>(rcv, cursor);
  k_scan<<<1, 1024, 0, stream>>>(cursor, row_st, cursor);
  k_fill<<<EE / 256, 256, 0, stream>>>(rcv, cursor, elist);
  k_nhist<<<NB, 256, 0, stream>>>(species, sbins, bcnt);
  k_nscan<<<1, 256, 0, stream>>>(sbins, bcnt, bbase, tspec);
  k_nfill<<<NB, 256, 0, stream>>>(species, bbase, nperm);
  k_up2<<<512, 256, 0, stream>>>(nf, fragw, s_up, v_up);
  for (int c = 0; c < 2; ++c) {
    k_mlp<<<EC / 64, 256, 0, stream>>>(re, elist, vecs, snd, fragw,
                                       s_up, v_up, wm, c * EC);
    k_gather<<<NN / 4, 256, 0, stream>>>(wm, row_st, acc, c * EC, (c + 1) * EC);
  }
  k_post2<<<NT_MAX / 2, 128, 0, stream>>>(nf, acc, fragw, Wsc, Wout,
                                          nperm, tspec, (float*)d_out);
}

// Round 13
// 333.217 us; speedup vs baseline: 3.5035x; 1.0599x over previous
//
#include <hip/hip_runtime.h>
#include <math.h>

// ---------------------------------------------------------------------------
// MACE layer, round 19: launch-level optimization only (compute kernels
// byte-identical to r18, 353.2us).
//  - Runtime-adaptive chunking: if ws_size fits wm for all EE edges
//    (~186.3 MB), run ONE k_mlp + ONE k_gather (pure-store path, no acc
//    re-read); else fall back to the exact r18 two-chunk schedule.
//  - Setup fusion: k_hist+=k_nhist (node part on blocks<NB), k_scan+=k_nscan
//    (single 1024-thread block), k_fill+=k_nfill. 3 fewer launches.
//
// Workspace (floats): base 13,017,472 f (52.07 MB) + wm:
//   two-chunk wm = EC*256 bf16 (64 MB, total ~116 MB)
//   one-chunk wm = EE*256 bf16 (134 MB, total ~186.3 MB; used only if
//   ws_size permits)
// ---------------------------------------------------------------------------

#define NN 32768
#define EE 262144
#define EC 131072                        // edges per chunk (fallback: 2 chunks)
#define ZZ 10
#define NB 128                           // NN/256 blocks for binning
#define NT_MAX 2064                      // >= ceil((NN + ZZ*15)/16), even
#define INV8 0.125f                      // 1/sqrt(64)
#define INV_SQRT8 0.35355339059327373f   // 1/sqrt(8)
#define INVZ 0.039528470752104741f       // 1/sqrt(64*10)
#define EPS_C 0.25f
#define RS2 0.70710678118654752f         // 1/sqrt(2)

typedef _Float16 f16;
typedef f16 f16x8 __attribute__((ext_vector_type(8)));
typedef f16 f16x4 __attribute__((ext_vector_type(4)));
typedef f16 f16x2 __attribute__((ext_vector_type(2)));
typedef float f32x4 __attribute__((ext_vector_type(4)));

#define LDFRAG(fid) (*(const f16x8*)(fragw + ((size_t)(fid) << 9) + (lane << 3)))

__device__ __forceinline__ unsigned bfpair(float lo, float hi) {
  unsigned ul = __float_as_uint(lo);
  unsigned uh = __float_as_uint(hi);
  ul = (ul + 0x7FFFu + ((ul >> 16) & 1u)) >> 16;
  uh = (uh + 0x7FFFu + ((uh >> 16) & 1u)) >> 16;
  return ul | (uh << 16);
}

__device__ __forceinline__ unsigned short f2h(float x) {
  union { f16 h; unsigned short u; } cv;
  cv.h = (f16)x;
  return cv.u;
}

__device__ __forceinline__ f16x8 pack8(float4 a, float4 b) {
  f16x8 r;
  r[0] = (f16)a.x; r[1] = (f16)a.y; r[2] = (f16)a.z; r[3] = (f16)a.w;
  r[4] = (f16)b.x; r[5] = (f16)b.y; r[6] = (f16)b.z; r[7] = (f16)b.w;
  return r;
}

__device__ __forceinline__ float silu_f(float x) {
  return x / (1.0f + __expf(-x));
}

// ---------------------------------------------------------------------------
// Weight fragment packing (unchanged from round 15).
// ---------------------------------------------------------------------------
__global__ __launch_bounds__(256) void k_frag(
    const float* __restrict__ W1, const float* __restrict__ W2,
    const float* __restrict__ W3, const float* __restrict__ W4,
    const float* __restrict__ Wdns, const float* __restrict__ Wdnv,
    const float* __restrict__ Wpss, const float* __restrict__ Wpsv,
    const float* __restrict__ Wsks, const float* __restrict__ Wskv,
    const float* __restrict__ Wups, const float* __restrict__ Wupv,
    unsigned short* __restrict__ fragw) {
  int id = blockIdx.x * 256 + threadIdx.x;
  if (id >= 268 * 64) return;
  int fid = id >> 6, lane = id & 63;
  int q = lane >> 4, c = lane & 15;
  const float* W; int K = 64, N = 64, t, ks; float sc; int w4 = 0;
  if (fid < 4)       { W = W1; K = 8; N = 64; t = fid; ks = 0; sc = INV_SQRT8; }
  else if (fid < 12) { W = W2; t = (fid - 4) >> 1;  ks = (fid - 4) & 1;  sc = INV8; }
  else if (fid < 20) { W = W3; t = (fid - 12) >> 1; ks = (fid - 12) & 1; sc = INV8; }
  else if (fid < 60) { W = W4; N = 320; t = (fid - 20) >> 1; ks = (fid - 20) & 1; sc = INV8; w4 = 1; }
  else {
    int f2 = fid - 60; sc = INV8;
    if (f2 < 8)        { W = Wdns; }
    else if (f2 < 16)  { W = Wdnv; f2 -= 8; }
    else if (f2 < 24)  { W = Wpss; f2 -= 16; }
    else if (f2 < 32)  { W = Wpsv; f2 -= 24; }
    else if (f2 < 112) { f2 -= 32; W = Wsks + (f2 >> 3) * 4096; f2 &= 7; sc = INVZ; }
    else if (f2 < 192) { f2 -= 112; W = Wskv + (f2 >> 3) * 4096; f2 &= 7; sc = INVZ; }
    else if (f2 < 200) { W = Wups; f2 -= 192; }
    else               { W = Wupv; f2 -= 200; }
    t = f2 >> 1; ks = f2 & 1;
  }
  int col = w4 ? ((t % 5) * 64 + 4 * c + (t / 5)) : (t * 16 + c);
  unsigned short o[8];
#pragma unroll
  for (int i = 0; i < 8; ++i) {
    int k = ks * 32 + 8 * q + i;
    float v = (k < K) ? W[k * N + col] * sc : 0.0f;
    o[i] = f2h(v);
  }
  *(uint4*)(fragw + (size_t)id * 8) = *(const uint4*)o;
}

// ---- fused: edge-receiver hist (all blocks) + node-species hist (<NB) ----
__global__ __launch_bounds__(256) void k_hist(
    const int* __restrict__ rcv, int* __restrict__ cnt,
    const int* __restrict__ species, int* __restrict__ sbins,
    int* __restrict__ bcnt) {
  __shared__ int h[ZZ];
  int t = threadIdx.x;
  int b = blockIdx.x;
  if (b < NB && t < ZZ) h[t] = 0;
  __syncthreads();
  int e = b * 256 + t;
  atomicAdd(&cnt[rcv[e]], 1);
  if (b < NB) {
    atomicAdd(&h[species[b * 256 + t]], 1);
    __syncthreads();
    if (t < ZZ) {
      bcnt[b * ZZ + t] = h[t];
      atomicAdd(&sbins[32 + t], h[t]);
    }
  }
}

// ---- fused: CSR scan (1024 thr) + species-bin scan/tspec ----
__global__ __launch_bounds__(1024) void k_scan(
    const int* __restrict__ cnt, int* __restrict__ row_start,
    int* __restrict__ cursor, int* __restrict__ sbins,
    const int* __restrict__ bcnt, int* __restrict__ bbase,
    int* __restrict__ tspec) {
  __shared__ int tot[1024];
  __shared__ int sb[12];
  int t = threadIdx.x;
  int base = t * 32;
  int local[32];
  int s = 0;
#pragma unroll
  for (int i = 0; i < 32; ++i) { local[i] = s; s += cnt[base + i]; }
  tot[t] = s;
  __syncthreads();
  for (int off = 1; off < 1024; off <<= 1) {
    int v = (t >= off) ? tot[t - off] : 0;
    __syncthreads();
    tot[t] += v;
    __syncthreads();
  }
  int prefix = (t == 0) ? 0 : tot[t - 1];
#pragma unroll
  for (int i = 0; i < 32; ++i) {
    int v = prefix + local[i];
    row_start[base + i] = v;
    cursor[base + i] = v;
  }
  if (t == 1023) row_start[NN] = prefix + s;
  // ---- species-bin part ----
  if (t == 0) {
    int off = 0;
    for (int z = 0; z < ZZ; ++z) {
      sb[z] = off;
      off += ((sbins[32 + z] + 15) >> 4) << 4;
    }
    sb[ZZ] = off;
  }
  __syncthreads();
  if (t < ZZ) {
    int run = sb[t];
    for (int b = 0; b < NB; ++b) {
      bbase[b * ZZ + t] = run;
      run += bcnt[b * ZZ + t];
    }
  }
  for (int i = t; i < NT_MAX; i += 1024) {
    int bb = i * 16, z = -1;
#pragma unroll
    for (int zz = 0; zz < ZZ; ++zz)
      if (bb >= sb[zz] && bb < sb[zz + 1]) z = zz;
    tspec[i] = z;
  }
}

// ---- fused: edge CSR fill (all blocks) + node perm fill (<NB) ----
__global__ __launch_bounds__(256) void k_fill(
    const int* __restrict__ rcv, int* __restrict__ cursor,
    int* __restrict__ elist, const int* __restrict__ species,
    const int* __restrict__ bbase, int* __restrict__ nperm) {
  __shared__ int cur[ZZ];
  int t = threadIdx.x;
  int b = blockIdx.x;
  if (b < NB && t < ZZ) cur[t] = bbase[b * ZZ + t];
  __syncthreads();
  int e = b * 256 + t;
  int pos = atomicAdd(&cursor[rcv[e]], 1);
  elist[pos] = e;
  if (b < NB) {
    int n = b * 256 + t;
    int p = atomicAdd(&cur[species[n]], 1);
    nperm[p] = n;
  }
}

// ---------------------------------------------------------------------------
// linear_up on MFMA (unchanged from round 10).
// ---------------------------------------------------------------------------
__global__ __launch_bounds__(256) void k_up2(
    const float* __restrict__ nf,
    const unsigned short* __restrict__ fragw,
    unsigned short* __restrict__ s_up, unsigned short* __restrict__ v_up) {
  int lane = threadIdx.x & 63;
  int wv = threadIdx.x >> 6;
  int n0 = (blockIdx.x * 4 + wv) * 16;
  int q = lane >> 4, c = lane & 15;
  const f32x4 zero4 = {0.f, 0.f, 0.f, 0.f};
  const float* nrow = nf + (size_t)(n0 + c) * 256;

  f16x8 aS[2], aX[2], aY[2], aZ[2];
#pragma unroll
  for (int ks = 0; ks < 2; ++ks) {
    int k0 = ks * 32 + 8 * q;
    aS[ks] = pack8(*(const float4*)(nrow + k0), *(const float4*)(nrow + k0 + 4));
    float vb[24];
    const float4* vp = (const float4*)(nrow + 64 + 3 * k0);
#pragma unroll
    for (int j = 0; j < 6; ++j) *(float4*)(vb + 4 * j) = vp[j];
#pragma unroll
    for (int i = 0; i < 8; ++i) {
      aX[ks][i] = (f16)vb[3 * i];
      aY[ks][i] = (f16)vb[3 * i + 1];
      aZ[ks][i] = (f16)vb[3 * i + 2];
    }
  }

  f32x4 os[4], ox[4], oy[4], oz[4];
#pragma unroll
  for (int t = 0; t < 4; ++t)
#pragma unroll
    for (int ks = 0; ks < 2; ++ks) {
      f16x8 bS = LDFRAG(252 + t * 2 + ks);
      f16x8 bV = LDFRAG(260 + t * 2 + ks);
      os[t] = __builtin_amdgcn_mfma_f32_16x16x32_f16(aS[ks], bS, ks ? os[t] : zero4, 0, 0, 0);
      ox[t] = __builtin_amdgcn_mfma_f32_16x16x32_f16(aX[ks], bV, ks ? ox[t] : zero4, 0, 0, 0);
      oy[t] = __builtin_amdgcn_mfma_f32_16x16x32_f16(aY[ks], bV, ks ? oy[t] : zero4, 0, 0, 0);
      oz[t] = __builtin_amdgcn_mfma_f32_16x16x32_f16(aZ[ks], bV, ks ? oz[t] : zero4, 0, 0, 0);
    }

#pragma unroll
  for (int t = 0; t < 4; ++t)
#pragma unroll
    for (int r = 0; r < 4; ++r) {
      int n = n0 + 4 * q + r;
      int ch = 16 * t + c;
      s_up[n * 64 + ch] = f2h(os[t][r]);
      v_up[(n * 3 + 0) * 64 + ch] = f2h(ox[t][r]);
      v_up[(n * 3 + 1) * 64 + ch] = f2h(oy[t][r]);
      v_up[(n * 3 + 2) * 64 + ch] = f2h(oz[t][r]);
    }
}

// ---------------------------------------------------------------------------
// Radial MLP + tensor product, fused (byte-identical to round 15).
// ---------------------------------------------------------------------------
__global__ __launch_bounds__(256, 4) void k_mlp(
    const float* __restrict__ re, const int* __restrict__ elist,
    const float* __restrict__ vecs, const int* __restrict__ snd,
    const unsigned short* __restrict__ fragw,
    const unsigned short* __restrict__ s_up,
    const unsigned short* __restrict__ v_up,
    unsigned short* __restrict__ wm, int ip0) {
  __shared__ float hs[4][1088];  // [wave][16 rows * 68]
  int lane = threadIdx.x & 63;
  int wv = threadIdx.x >> 6;
  int q = lane >> 4, c = lane & 15;
  int ipb = ip0 + (blockIdx.x * 4 + wv) * 16;
  float* hw = hs[wv];
  const f32x4 zero4 = {0.f, 0.f, 0.f, 0.f};

  // ---- layer 1 ----
  f16x8 a1 = {0, 0, 0, 0, 0, 0, 0, 0};
  if (q == 0) {
    int e = elist[ipb + c];
    const float4* rp = (const float4*)(re + (size_t)e * 8);
    a1 = pack8(rp[0], rp[1]);
  }
  {
    f32x4 acc[4];
#pragma unroll
    for (int t = 0; t < 4; ++t)
      acc[t] = __builtin_amdgcn_mfma_f32_16x16x32_f16(a1, LDFRAG(t), zero4, 0, 0, 0);
#pragma unroll
    for (int t = 0; t < 4; ++t)
#pragma unroll
      for (int r = 0; r < 4; ++r) {
        float x = silu_f(acc[t][r]);
        hw[(4 * q + r) * 68 + ((16 * t + c) ^ (r << 3))] = x;
      }
  }

  // ---- layers 2 and 3 ----
#pragma unroll
  for (int L = 0; L < 2; ++L) {
    int base = 4 + 8 * L;
    f16x8 af0, af1;
    {
      const float* hp = hw + c * 68 + 8 * (q ^ (c & 3));
      af0 = pack8(*(const float4*)hp, *(const float4*)(hp + 4));
      af1 = pack8(*(const float4*)(hp + 32), *(const float4*)(hp + 36));
    }
    f32x4 acc[4];
#pragma unroll
    for (int t = 0; t < 4; ++t) {
      acc[t] = __builtin_amdgcn_mfma_f32_16x16x32_f16(af0, LDFRAG(base + t * 2), zero4, 0, 0, 0);
      acc[t] = __builtin_amdgcn_mfma_f32_16x16x32_f16(af1, LDFRAG(base + t * 2 + 1), acc[t], 0, 0, 0);
    }
#pragma unroll
    for (int t = 0; t < 4; ++t)
#pragma unroll
      for (int r = 0; r < 4; ++r) {
        float x = silu_f(acc[t][r]);
        hw[(4 * q + r) * 68 + ((16 * t + c) ^ (r << 3))] = x;
      }
  }

  // ---- layer 4 A-fragments (hs read-only from here) ----
  f16x8 a4k0, a4k1;
  {
    const float* hp = hw + c * 68 + 8 * (q ^ (c & 3));
    a4k0 = pack8(*(const float4*)hp, *(const float4*)(hp + 4));
    a4k1 = pack8(*(const float4*)(hp + 32), *(const float4*)(hp + 36));
  }

  // ---- edge geometry for this lane's 4 rows ----
  int se_[4];
  float Yx[4], Yy[4], Yz[4];
#pragma unroll
  for (int r = 0; r < 4; ++r) {
    int e = elist[ipb + 4 * q + r];
    float ex = vecs[(size_t)e * 3 + 0];
    float ey = vecs[(size_t)e * 3 + 1];
    float ez = vecs[(size_t)e * 3 + 2];
    float rn = 1.0f / (sqrtf(ex * ex + ey * ey + ez * ez) + 1e-9f);
    Yx[r] = ex * rn; Yy[r] = ey * rn; Yz[r] = ez * rn;
    se_[r] = snd[e];
  }

  // ---- layer 4 + TP, two pair-passes (channels 4c+2pg, 4c+2pg+1) ----
  size_t orow = (size_t)(ipb - ip0);
#pragma unroll 1
  for (int pg = 0; pg < 2; ++pg) {
    f16x2 gs[4], gx[4], gy[4], gz[4];
#pragma unroll
    for (int r = 0; r < 4; ++r) {
      const unsigned short* sr = s_up + (size_t)se_[r] * 64 + 4 * c + 2 * pg;
      const unsigned short* vr = v_up + (size_t)se_[r] * 192 + 4 * c + 2 * pg;
      gs[r] = *(const f16x2*)sr;
      gx[r] = *(const f16x2*)vr;
      gy[r] = *(const f16x2*)(vr + 64);
      gz[r] = *(const f16x2*)(vr + 128);
    }
    float pms[4], pmx[4], pmy[4], pmz[4];
#pragma unroll
    for (int ig2 = 0; ig2 < 2; ++ig2) {
      int ig = 2 * pg + ig2;
      f32x4 o[5];
#pragma unroll
      for (int p = 0; p < 5; ++p) {
        o[p] = __builtin_amdgcn_mfma_f32_16x16x32_f16(
            a4k0, LDFRAG(20 + (ig * 5 + p) * 2 + 0), zero4, 0, 0, 0);
        o[p] = __builtin_amdgcn_mfma_f32_16x16x32_f16(
            a4k1, LDFRAG(20 + (ig * 5 + p) * 2 + 1), o[p], 0, 0, 0);
      }
#pragma unroll
      for (int r = 0; r < 4; ++r) {
        float ss = (float)gs[r][ig2];
        float vx = (float)gx[r][ig2], vy = (float)gy[r][ig2], vz = (float)gz[r][ig2];
        float dt = vx * Yx[r] + vy * Yy[r] + vz * Yz[r];
        float cx = vy * Yz[r] - vz * Yy[r];
        float cy = vz * Yx[r] - vx * Yz[r];
        float cz = vx * Yy[r] - vy * Yx[r];
        float ms = EPS_C * (o[0][r] * ss + o[3][r] * dt);
        float mx = EPS_C * (o[1][r] * Yx[r] + o[2][r] * vx + o[4][r] * (cx * RS2));
        float my = EPS_C * (o[1][r] * Yy[r] + o[2][r] * vy + o[4][r] * (cy * RS2));
        float mz = EPS_C * (o[1][r] * Yz[r] + o[2][r] * vz + o[4][r] * (cz * RS2));
        if (ig2 == 0) {
          pms[r] = ms; pmx[r] = mx; pmy[r] = my; pmz[r] = mz;
        } else {
          // permuted layout: short off = comp*64 + pg*32 + 2c (low = even ch)
          unsigned short* wr = wm + (orow + 4 * q + r) * 256 + pg * 32 + 2 * c;
          *(unsigned*)(wr)       = bfpair(pms[r], ms);
          *(unsigned*)(wr + 64)  = bfpair(pmx[r], mx);
          *(unsigned*)(wr + 128) = bfpair(pmy[r], my);
          *(unsigned*)(wr + 192) = bfpair(pmz[r], mz);
        }
      }
    }
  }
}

// one wave per node; contiguous clipped CSR range [lo,hi). Lane g reads one
// contiguous uint2 (shorts 4g..4g+3 of the permuted row): comp = g>>4,
// pg = (g&15)>>3, cc = 2*(g&7) -> channels {4cc+2pg, +1, 4cc+4+2pg, +1};
// acc store = two float2. Chunk 0 (e0==0) stores unconditionally.
__global__ __launch_bounds__(256) void k_gather(
    const unsigned short* __restrict__ m_buf,
    const int* __restrict__ row_start,
    float* __restrict__ acc, int e0, int e1) {
  int g = threadIdx.x & 63;
  int wv = threadIdx.x >> 6;
  int n = blockIdx.x * 4 + wv;
  int beg = row_start[n], end = row_start[n + 1];
  int lo = beg > e0 ? beg : e0;
  int hi = end < e1 ? end : e1;
  if (e0 > 0 && lo >= hi) return;
  float2 a0 = make_float2(0.f, 0.f);
  float2 a1 = make_float2(0.f, 0.f);
  for (int i = lo; i < hi; ++i) {
    uint2 m = *(const uint2*)(m_buf + (size_t)(i - e0) * 256 + g * 4);
    a0.x += __uint_as_float(m.x << 16);
    a0.y += __uint_as_float(m.x & 0xFFFF0000u);
    a1.x += __uint_as_float(m.y << 16);
    a1.y += __uint_as_float(m.y & 0xFFFF0000u);
  }
  int comp = g >> 4;
  int pg = (g & 15) >> 3;
  int cc = 2 * (g & 7);
  float* d0 = acc + (size_t)n * 256 + comp * 64 + 4 * cc + 2 * pg;
  float* d1 = d0 + 4;
  if (e0 == 0) {
    *(float2*)d0 = a0;
    *(float2*)d1 = a1;
  } else {
    float2 p0 = *(const float2*)d0;
    float2 p1 = *(const float2*)d1;
    *(float2*)d0 = make_float2(a0.x + p0.x, a0.y + p0.y);
    *(float2*)d1 = make_float2(a1.x + p1.x, a1.y + p1.y);
  }
}

// ---------------------------------------------------------------------------
// Post stage on MFMA (unchanged from round 8).
// ---------------------------------------------------------------------------
__global__ __launch_bounds__(128) void k_post2(
    const float* __restrict__ nf, const float* __restrict__ acc,
    const unsigned short* __restrict__ fragw,
    const float* __restrict__ Wsc, const float* __restrict__ Wout,
    const int* __restrict__ nperm, const int* __restrict__ tspec,
    float* __restrict__ out) {
  __shared__ float hs[2][2][1088];
  int lane = threadIdx.x & 63;
  int wv = threadIdx.x >> 6;
  int tt = blockIdx.x * 2 + wv;
  int spec = tspec[tt];
  if (spec < 0) return;
  int q = lane >> 4, c = lane & 15;
  float* hw0 = hs[wv][0];
  float* hw1 = hs[wv][1];
  const f32x4 zero4 = {0.f, 0.f, 0.f, 0.f};

  int nA = nperm[tt * 16 + c];
  size_t rowA = (size_t)((nA < 0) ? 0 : nA);
  const float* arow = acc + rowA * 256;
  const float* nrow = nf + rowA * 256;

  // A-fragments: down (from acc) and skip (from nf)
  f16x8 aS[2], aVX[2], aVY[2], aVZ[2];
  f16x8 kS[2], kX[2], kY[2], kZ[2];
#pragma unroll
  for (int ks = 0; ks < 2; ++ks) {
    int k0 = ks * 32 + 8 * q;
    aS[ks]  = pack8(*(const float4*)(arow + k0),       *(const float4*)(arow + k0 + 4));
    aVX[ks] = pack8(*(const float4*)(arow + 64 + k0),  *(const float4*)(arow + 68 + k0));
    aVY[ks] = pack8(*(const float4*)(arow + 128 + k0), *(const float4*)(arow + 132 + k0));
    aVZ[ks] = pack8(*(const float4*)(arow + 192 + k0), *(const float4*)(arow + 196 + k0));
    kS[ks]  = pack8(*(const float4*)(nrow + k0),       *(const float4*)(nrow + k0 + 4));
    float vb[24];
    const float4* vp = (const float4*)(nrow + 64 + 3 * k0);
#pragma unroll
    for (int j = 0; j < 6; ++j) *(float4*)(vb + 4 * j) = vp[j];
#pragma unroll
    for (int i = 0; i < 8; ++i) {
      kX[ks][i] = (f16)vb[3 * i];
      kY[ks][i] = (f16)vb[3 * i + 1];
      kZ[ks][i] = (f16)vb[3 * i + 2];
    }
  }

  // down linear (INV8 in B)
  f32x4 ds[4], dvx[4], dvy[4], dvz[4];
#pragma unroll
  for (int t = 0; t < 4; ++t)
#pragma unroll
    for (int ks = 0; ks < 2; ++ks) {
      f16x8 bS = LDFRAG(60 + t * 2 + ks);
      f16x8 bV = LDFRAG(68 + t * 2 + ks);
      ds[t]  = __builtin_amdgcn_mfma_f32_16x16x32_f16(aS[ks],  bS, ks ? ds[t]  : zero4, 0, 0, 0);
      dvx[t] = __builtin_amdgcn_mfma_f32_16x16x32_f16(aVX[ks], bV, ks ? dvx[t] : zero4, 0, 0, 0);
      dvy[t] = __builtin_amdgcn_mfma_f32_16x16x32_f16(aVY[ks], bV, ks ? dvy[t] : zero4, 0, 0, 0);
      dvz[t] = __builtin_amdgcn_mfma_f32_16x16x32_f16(aVZ[ks], bV, ks ? dvz[t] : zero4, 0, 0, 0);
    }

  // skip linear (INVZ in B) -> initializes post accumulators
  f32x4 ps[4], pvx[4], pvy[4], pvz[4];
#pragma unroll
  for (int t = 0; t < 4; ++t)
#pragma unroll
    for (int ks = 0; ks < 2; ++ks) {
      f16x8 bs = LDFRAG(92 + spec * 8 + t * 2 + ks);
      f16x8 bv = LDFRAG(172 + spec * 8 + t * 2 + ks);
      ps[t]  = __builtin_amdgcn_mfma_f32_16x16x32_f16(kS[ks], bs, ks ? ps[t]  : zero4, 0, 0, 0);
      pvx[t] = __builtin_amdgcn_mfma_f32_16x16x32_f16(kX[ks], bv, ks ? pvx[t] : zero4, 0, 0, 0);
      pvy[t] = __builtin_amdgcn_mfma_f32_16x16x32_f16(kY[ks], bv, ks ? pvy[t] : zero4, 0, 0, 0);
      pvz[t] = __builtin_amdgcn_mfma_f32_16x16x32_f16(kZ[ks], bv, ks ? pvz[t] : zero4, 0, 0, 0);
    }

  // symmetric contraction, elementwise in C/D layout
  f32x4 so[4], vcm[4];
  const float* wzp = Wsc + spec * 576 + c;
#pragma unroll
  for (int t = 0; t < 4; ++t) {
    int col = 16 * t;
    float w0 = wzp[col], w1 = wzp[64 + col], w2 = wzp[128 + col];
    float w3 = wzp[192 + col], w4 = wzp[256 + col];
    float w5 = wzp[320 + col], w6 = wzp[384 + col];
    float w7 = wzp[448 + col], w8 = wzp[512 + col];
#pragma unroll
    for (int r = 0; r < 4; ++r) {
      float s = ds[t][r];
      float vx = dvx[t][r], vy = dvy[t][r], vz = dvz[t][r];
      float vn2 = vx * vx + vy * vy + vz * vz;
      so[t][r]  = w0 * s + w1 * s * s + w2 * vn2 + w3 * s * s * s + w4 * s * vn2;
      vcm[t][r] = w5 + w6 * s + w7 * s * s + w8 * vn2;
    }
  }

  // post linear pass 1: s_o and vx (INV8 in B)
#pragma unroll
  for (int t = 0; t < 4; ++t)
#pragma unroll
    for (int r = 0; r < 4; ++r) {
      int ad = (4 * q + r) * 68 + ((16 * t + c) ^ (r << 3));
      hw0[ad] = so[t][r];
      hw1[ad] = vcm[t][r] * dvx[t][r];
    }
  {
    f16x8 aP0[2], aP1[2];
#pragma unroll
    for (int ks = 0; ks < 2; ++ks) {
      const float* hp0 = hw0 + c * 68 + ks * 32 + 8 * (q ^ (c & 3));
      const float* hp1 = hw1 + c * 68 + ks * 32 + 8 * (q ^ (c & 3));
      aP0[ks] = pack8(*(const float4*)hp0, *(const float4*)(hp0 + 4));
      aP1[ks] = pack8(*(const float4*)hp1, *(const float4*)(hp1 + 4));
    }
#pragma unroll
    for (int t = 0; t < 4; ++t)
#pragma unroll
      for (int ks = 0; ks < 2; ++ks) {
        ps[t]  = __builtin_amdgcn_mfma_f32_16x16x32_f16(aP0[ks], LDFRAG(76 + t * 2 + ks), ps[t], 0, 0, 0);
        pvx[t] = __builtin_amdgcn_mfma_f32_16x16x32_f16(aP1[ks], LDFRAG(84 + t * 2 + ks), pvx[t], 0, 0, 0);
      }
  }
  // post linear pass 2: vy and vz
#pragma unroll
  for (int t = 0; t < 4; ++t)
#pragma unroll
    for (int r = 0; r < 4; ++r) {
      int ad = (4 * q + r) * 68 + ((16 * t + c) ^ (r << 3));
      hw0[ad] = vcm[t][r] * dvy[t][r];
      hw1[ad] = vcm[t][r] * dvz[t][r];
    }
  {
    f16x8 aP0[2], aP1[2];
#pragma unroll
    for (int ks = 0; ks < 2; ++ks) {
      const float* hp0 = hw0 + c * 68 + ks * 32 + 8 * (q ^ (c & 3));
      const float* hp1 = hw1 + c * 68 + ks * 32 + 8 * (q ^ (c & 3));
      aP0[ks] = pack8(*(const float4*)hp0, *(const float4*)(hp0 + 4));
      aP1[ks] = pack8(*(const float4*)hp1, *(const float4*)(hp1 + 4));
    }
#pragma unroll
    for (int t = 0; t < 4; ++t)
#pragma unroll
      for (int ks = 0; ks < 2; ++ks) {
        pvy[t] = __builtin_amdgcn_mfma_f32_16x16x32_f16(aP0[ks], LDFRAG(84 + t * 2 + ks), pvy[t], 0, 0, 0);
        pvz[t] = __builtin_amdgcn_mfma_f32_16x16x32_f16(aP1[ks], LDFRAG(84 + t * 2 + ks), pvz[t], 0, 0, 0);
      }
  }

  // outputs: features + scalar head
  float wo[4];
#pragma unroll
  for (int t = 0; t < 4; ++t) wo[t] = Wout[16 * t + c];
  int nst[4];
#pragma unroll
  for (int r = 0; r < 4; ++r) nst[r] = nperm[tt * 16 + 4 * q + r];
#pragma unroll
  for (int r = 0; r < 4; ++r) {
    float part = 0.f;
#pragma unroll
    for (int t = 0; t < 4; ++t) part += ps[t][r] * wo[t];
    part += __shfl_xor(part, 1);
    part += __shfl_xor(part, 2);
    part += __shfl_xor(part, 4);
    part += __shfl_xor(part, 8);
    int n = nst[r];
    if (n >= 0) {
      float* orow = out + NN + (size_t)n * 256;
#pragma unroll
      for (int t = 0; t < 4; ++t) {
        int col = 16 * t + c;
        orow[col] = ps[t][r];
        orow[64 + col * 3 + 0] = pvx[t][r];
        orow[64 + col * 3 + 1] = pvy[t][r];
        orow[64 + col * 3 + 2] = pvz[t][r];
      }
      if (c == 0) out[n] = part * INV8;
    }
  }
}

extern "C" void kernel_launch(void* const* d_in, const int* in_sizes, int n_in,
                              void* d_out, int out_size, void* d_ws, size_t ws_size,
                              hipStream_t stream) {
  (void)in_sizes; (void)n_in; (void)out_size;
  const float* vecs = (const float*)d_in[0];
  const float* nf   = (const float*)d_in[1];
  const float* re   = (const float*)d_in[2];
  const float* Wsks = (const float*)d_in[3];
  const float* Wskv = (const float*)d_in[4];
  const float* Wups = (const float*)d_in[5];
  const float* Wupv = (const float*)d_in[6];
  const float* W1   = (const float*)d_in[7];
  const float* W2   = (const float*)d_in[8];
  const float* W3   = (const float*)d_in[9];
  const float* W4   = (const float*)d_in[10];
  const float* Wdns = (const float*)d_in[11];
  const float* Wdnv = (const float*)d_in[12];
  const float* Wsc  = (const float*)d_in[13];
  const float* Wpss = (const float*)d_in[14];
  const float* Wpsv = (const float*)d_in[15];
  const float* Wout = (const float*)d_in[16];
  const int* species = (const int*)d_in[17];
  const int* snd     = (const int*)d_in[18];
  const int* rcv     = (const int*)d_in[19];

  float* ws = (float*)d_ws;
  unsigned short* s_up  = (unsigned short*)ws;              // N*64 f16
  unsigned short* v_up  = (unsigned short*)(ws + 1048576);  // N*192 f16
  float* acc   = ws + 4194304;                              // N*256 f32
  unsigned short* fragw = (unsigned short*)(ws + 12582912); // 268 frags
  int* row_st  = (int*)(ws + 12651520);                     // 32832
  int* cursor  = (int*)(ws + 12684352);                     // 32768
  int* elist   = (int*)(ws + 12717120);                     // 262144
  int* nperm   = (int*)(ws + 12979264);                     // 33280
  int* tspec   = (int*)(ws + 13012544);                     // 2304
  int* sbins   = (int*)(ws + 13014848);                     // 64
  int* bcnt    = (int*)(ws + 13014912);                     // 1280
  int* bbase   = (int*)(ws + 13016192);                     // 1280
  unsigned short* wm = (unsigned short*)(ws + 13017472);    // bf16 msg buffer

  // single-chunk if ws fits wm for all EE edges (52,069,888 + 134,217,728 B)
  size_t need1 = 52069888ull + (size_t)EE * 512ull;
  int ecs = (ws_size >= need1) ? EE : EC;
  int nchunk = EE / ecs;

  hipMemsetAsync(cursor, 0, NN * sizeof(int), stream);
  hipMemsetAsync(sbins, 0, 64 * sizeof(int), stream);
  hipMemsetAsync(nperm, 0xFF, NT_MAX * 16 * sizeof(int), stream);
  k_frag<<<67, 256, 0, stream>>>(W1, W2, W3, W4, Wdns, Wdnv, Wpss, Wpsv,
                                 Wsks, Wskv, Wups, Wupv, fragw);
  k_hist<<<EE / 256, 256, 0, stream>>>(rcv, cursor, species, sbins, bcnt);
  k_scan<<<1, 1024, 0, stream>>>(cursor, row_st, cursor, sbins, bcnt, bbase,
                                 tspec);
  k_fill<<<EE / 256, 256, 0, stream>>>(rcv, cursor, elist, species, bbase,
                                       nperm);
  k_up2<<<512, 256, 0, stream>>>(nf, fragw, s_up, v_up);
  for (int c = 0; c < nchunk; ++c) {
    k_mlp<<<ecs / 64, 256, 0, stream>>>(re, elist, vecs, snd, fragw,
                                        s_up, v_up, wm, c * ecs);
    k_gather<<<NN / 4, 256, 0, stream>>>(wm, row_st, acc, c * ecs,
                                         (c + 1) * ecs);
  }
  k_post2<<<NT_MAX / 2, 128, 0, stream>>>(nf, acc, fragw, Wsc, Wout,
                                          nperm, tspec, (float*)d_out);
}